// Round 1
// baseline (648.404 us; speedup 1.0000x reference)
//
#include <hip/hip_runtime.h>
#include <math.h>

#define B_ 64
#define S_ 64
#define U_ 16
#define EMB_ 10
#define D_ 34
#define DD_ 3
#define FF_ 4
#define NL_ 4

// ---------------------------------------------------------------------------
// Kernel A: embedding + pos-encoding quirk + 4 post-norm encoder layers +
// final LN + projection to memory[B,S,3] (stored in d_ws).
// One block per batch element, 128 threads (2 waves).
// ---------------------------------------------------------------------------
__global__ __launch_bounds__(128) void enc_kernel(
    const float* __restrict__ src, const float* __restrict__ wemb,
    const float* __restrict__ semb,
    const float* __restrict__ qkv_w, const float* __restrict__ qkv_b,
    const float* __restrict__ out_w, const float* __restrict__ out_b,
    const float* __restrict__ ln1_w, const float* __restrict__ ln1_b,
    const float* __restrict__ lin1_w, const float* __restrict__ lin1_b,
    const float* __restrict__ lin2_w, const float* __restrict__ lin2_b,
    const float* __restrict__ ln2_w, const float* __restrict__ ln2_b,
    const float* __restrict__ norm_w, const float* __restrict__ norm_b,
    const float* __restrict__ eo_w, const float* __restrict__ eo_b,
    float* __restrict__ mem, float* __restrict__ out)
{
    const int b = blockIdx.x;
    const int tid = threadIdx.x;

    __shared__ float xs[S_][D_ + 1];
    __shared__ float qs[S_][D_];
    __shared__ float ks[S_][D_];
    __shared__ float vs[S_][D_];
    __shared__ float att[S_][D_];
    __shared__ float ffh[S_][FF_];
    __shared__ float tmp[S_][D_ + 1];

    // ---- embed_lyrics + positional encoding (pe row b added to ALL positions)
    const float negln = -logf(10000.0f) / (float)D_;
    for (int idx = tid; idx < S_ * D_; idx += 128) {
        int pos = idx / D_, d = idx % D_;
        float v;
        if (d < U_ - 2) {
            v = src[(b * S_ + pos) * U_ + d];
        } else if (d < U_ - 2 + EMB_) {
            int wi = (int)src[(b * S_ + pos) * U_ + (U_ - 2)];
            v = wemb[wi * EMB_ + (d - (U_ - 2))];
        } else {
            int si = (int)src[(b * S_ + pos) * U_ + (U_ - 1)];
            v = semb[si * EMB_ + (d - (U_ - 2 + EMB_))];
        }
        int k = d >> 1;
        float div = expf((float)(2 * k) * negln);
        float ang = (float)b * div;
        v += (d & 1) ? cosf(ang) : sinf(ang);
        xs[pos][d] = v;
    }
    __syncthreads();

    const float rs17 = 0.24253562503633297f;  // 1/sqrt(17)

    for (int l = 0; l < NL_; ++l) {
        // ---- qkv projection
        const float* Wqkv = qkv_w + l * 3 * D_ * D_;
        const float* bqkv = qkv_b + l * 3 * D_;
        for (int idx = tid; idx < S_ * 3 * D_; idx += 128) {
            int pos = idx / (3 * D_), r = idx % (3 * D_);
            const float* wrow = Wqkv + r * D_;
            float acc = bqkv[r];
            #pragma unroll
            for (int d = 0; d < D_; ++d) acc += xs[pos][d] * wrow[d];
            if (r < D_)          qs[pos][r] = acc;
            else if (r < 2 * D_) ks[pos][r - D_] = acc;
            else                 vs[pos][r - 2 * D_] = acc;
        }
        __syncthreads();

        // ---- attention: thread = h*64 + qi ; single-pass softmax (no max sub,
        // scores are O(few) in fp32 -> safe)
        {
            int h = tid >> 6, qi = tid & 63;
            int off = h * 17;
            float qv[17], acc[17];
            #pragma unroll
            for (int d = 0; d < 17; ++d) { qv[d] = qs[qi][off + d]; acc[d] = 0.f; }
            float ssum = 0.f;
            for (int j = 0; j < S_; ++j) {
                float sc = 0.f;
                #pragma unroll
                for (int d = 0; d < 17; ++d) sc += qv[d] * ks[j][off + d];
                float e = expf(sc * rs17);
                ssum += e;
                #pragma unroll
                for (int d = 0; d < 17; ++d) acc[d] += e * vs[j][off + d];
            }
            float inv = 1.f / ssum;
            #pragma unroll
            for (int d = 0; d < 17; ++d) att[qi][off + d] = acc[d] * inv;
        }
        __syncthreads();

        // ---- out proj + residual
        const float* Wo = out_w + l * D_ * D_;
        const float* bo = out_b + l * D_;
        for (int idx = tid; idx < S_ * D_; idx += 128) {
            int pos = idx / D_, d = idx % D_;
            const float* wrow = Wo + d * D_;
            float acc = bo[d];
            #pragma unroll
            for (int e = 0; e < D_; ++e) acc += att[pos][e] * wrow[e];
            tmp[pos][d] = xs[pos][d] + acc;
        }
        __syncthreads();

        // ---- LN1
        if (tid < S_) {
            int row = tid;
            float mu = 0.f;
            for (int d = 0; d < D_; ++d) mu += tmp[row][d];
            mu *= (1.0f / D_);
            float var = 0.f;
            for (int d = 0; d < D_; ++d) { float t = tmp[row][d] - mu; var += t * t; }
            var *= (1.0f / D_);
            float rstd = rsqrtf(var + 1e-5f);
            const float* w = ln1_w + l * D_;
            const float* bb = ln1_b + l * D_;
            for (int d = 0; d < D_; ++d)
                xs[row][d] = (tmp[row][d] - mu) * rstd * w[d] + bb[d];
        }
        __syncthreads();

        // ---- FF1 (34 -> 4, relu)
        const float* W1 = lin1_w + l * FF_ * D_;
        const float* b1 = lin1_b + l * FF_;
        for (int idx = tid; idx < S_ * FF_; idx += 128) {
            int pos = idx / FF_, f = idx % FF_;
            const float* wrow = W1 + f * D_;
            float acc = b1[f];
            #pragma unroll
            for (int d = 0; d < D_; ++d) acc += xs[pos][d] * wrow[d];
            ffh[pos][f] = fmaxf(acc, 0.f);
        }
        __syncthreads();

        // ---- FF2 (4 -> 34) + residual
        const float* W2 = lin2_w + l * D_ * FF_;
        const float* b2 = lin2_b + l * D_;
        for (int idx = tid; idx < S_ * D_; idx += 128) {
            int pos = idx / D_, d = idx % D_;
            const float* wrow = W2 + d * FF_;
            float acc = b2[d];
            #pragma unroll
            for (int f = 0; f < FF_; ++f) acc += ffh[pos][f] * wrow[f];
            tmp[pos][d] = xs[pos][d] + acc;
        }
        __syncthreads();

        // ---- LN2
        if (tid < S_) {
            int row = tid;
            float mu = 0.f;
            for (int d = 0; d < D_; ++d) mu += tmp[row][d];
            mu *= (1.0f / D_);
            float var = 0.f;
            for (int d = 0; d < D_; ++d) { float t = tmp[row][d] - mu; var += t * t; }
            var *= (1.0f / D_);
            float rstd = rsqrtf(var + 1e-5f);
            const float* w = ln2_w + l * D_;
            const float* bb = ln2_b + l * D_;
            for (int d = 0; d < D_; ++d)
                xs[row][d] = (tmp[row][d] - mu) * rstd * w[d] + bb[d];
        }
        __syncthreads();
    }

    // ---- final LayerNorm (norm_w/norm_b)
    if (tid < S_) {
        int row = tid;
        float mu = 0.f;
        for (int d = 0; d < D_; ++d) mu += xs[row][d];
        mu *= (1.0f / D_);
        float var = 0.f;
        for (int d = 0; d < D_; ++d) { float t = xs[row][d] - mu; var += t * t; }
        var *= (1.0f / D_);
        float rstd = rsqrtf(var + 1e-5f);
        for (int d = 0; d < D_; ++d)
            xs[row][d] = (xs[row][d] - mu) * rstd * norm_w[d] + norm_b[d];
    }
    __syncthreads();

    // ---- memory = x @ eo_w.T + eo_b  -> d_ws
    for (int idx = tid; idx < S_ * DD_; idx += 128) {
        int pos = idx / DD_, r = idx % DD_;
        const float* wrow = eo_w + r * D_;
        float acc = eo_b[r];
        #pragma unroll
        for (int d = 0; d < D_; ++d) acc += xs[pos][d] * wrow[d];
        mem[(b * S_ + pos) * DD_ + r] = acc;
    }

    // ---- pass-through output columns 3,4 (word / syllable idx)
    for (int pos = tid; pos < S_; pos += 128) {
        out[(b * S_ + pos) * 5 + 3] = src[(b * S_ + pos) * U_ + (U_ - 2)];
        out[(b * S_ + pos) * 5 + 4] = src[(b * S_ + pos) * U_ + (U_ - 1)];
    }
}

// ---------------------------------------------------------------------------
// Kernel B: incremental autoregressive decoder. One block = one wave = one
// batch element. Lane j owns position j's self-attn K/V and cross-attn K/V.
// 63 sequential steps; softmax via exp + butterfly shuffle wave-sums.
// ---------------------------------------------------------------------------
__device__ __forceinline__ float wsum(float v) {
    v += __shfl_xor(v, 1, 64);
    v += __shfl_xor(v, 2, 64);
    v += __shfl_xor(v, 4, 64);
    v += __shfl_xor(v, 8, 64);
    v += __shfl_xor(v, 16, 64);
    v += __shfl_xor(v, 32, 64);
    return v;
}

__device__ __forceinline__ void cpy64(float* dst, const float* s, int n, int lane) {
    for (int t = lane; t < n; t += 64) dst[t] = s[t];
}

__device__ __forceinline__ void ln3(float z0, float z1, float z2,
                                    const float* w, const float* bb,
                                    float& o0, float& o1, float& o2) {
    float mu = (z0 + z1 + z2) * (1.0f / 3.0f);
    float d0 = z0 - mu, d1 = z1 - mu, d2 = z2 - mu;
    float var = (d0 * d0 + d1 * d1 + d2 * d2) * (1.0f / 3.0f);
    float rstd = rsqrtf(var + 1e-5f);
    o0 = d0 * rstd * w[0] + bb[0];
    o1 = d1 * rstd * w[1] + bb[1];
    o2 = d2 * rstd * w[2] + bb[2];
}

__global__ __launch_bounds__(64) void dec_kernel(
    const float* __restrict__ mem,
    const float* __restrict__ sa_qkv_w, const float* __restrict__ sa_qkv_b,
    const float* __restrict__ sa_out_w, const float* __restrict__ sa_out_b,
    const float* __restrict__ gln1_w, const float* __restrict__ gln1_b,
    const float* __restrict__ ca_qkv_w, const float* __restrict__ ca_qkv_b,
    const float* __restrict__ ca_out_w, const float* __restrict__ ca_out_b,
    const float* __restrict__ gln2_w, const float* __restrict__ gln2_b,
    const float* __restrict__ l1_w, const float* __restrict__ l1_b,
    const float* __restrict__ l2_w, const float* __restrict__ l2_b,
    const float* __restrict__ gln3_w, const float* __restrict__ gln3_b,
    float* __restrict__ out)
{
    const int b = blockIdx.x;
    const int lane = threadIdx.x;

    // weights staged once in LDS (uniform-address reads broadcast, off the
    // y->y dependence chain)
    __shared__ float wsq[NL_][9][3];  __shared__ float bsq[NL_][9];
    __shared__ float wso[NL_][3][3]; __shared__ float bso[NL_][3];
    __shared__ float wn1[NL_][3];    __shared__ float bn1[NL_][3];
    __shared__ float wcq[NL_][9][3]; __shared__ float bcq[NL_][9];
    __shared__ float wco[NL_][3][3]; __shared__ float bco[NL_][3];
    __shared__ float wn2[NL_][3];    __shared__ float bn2[NL_][3];
    __shared__ float wf1[NL_][4][3]; __shared__ float bf1[NL_][4];
    __shared__ float wf2[NL_][3][4]; __shared__ float bf2[NL_][3];
    __shared__ float wn3[NL_][3];    __shared__ float bn3[NL_][3];

    cpy64(&wsq[0][0][0], sa_qkv_w, NL_ * 27, lane);
    cpy64(&bsq[0][0],    sa_qkv_b, NL_ * 9,  lane);
    cpy64(&wso[0][0][0], sa_out_w, NL_ * 9,  lane);
    cpy64(&bso[0][0],    sa_out_b, NL_ * 3,  lane);
    cpy64(&wn1[0][0],    gln1_w,   NL_ * 3,  lane);
    cpy64(&bn1[0][0],    gln1_b,   NL_ * 3,  lane);
    cpy64(&wcq[0][0][0], ca_qkv_w, NL_ * 27, lane);
    cpy64(&bcq[0][0],    ca_qkv_b, NL_ * 9,  lane);
    cpy64(&wco[0][0][0], ca_out_w, NL_ * 9,  lane);
    cpy64(&bco[0][0],    ca_out_b, NL_ * 3,  lane);
    cpy64(&wn2[0][0],    gln2_w,   NL_ * 3,  lane);
    cpy64(&bn2[0][0],    gln2_b,   NL_ * 3,  lane);
    cpy64(&wf1[0][0][0], l1_w,     NL_ * 12, lane);
    cpy64(&bf1[0][0],    l1_b,     NL_ * 4,  lane);
    cpy64(&wf2[0][0][0], l2_w,     NL_ * 12, lane);
    cpy64(&bf2[0][0],    l2_b,     NL_ * 3,  lane);
    cpy64(&wn3[0][0],    gln3_w,   NL_ * 3,  lane);
    cpy64(&bn3[0][0],    gln3_b,   NL_ * 3,  lane);
    __syncthreads();

    // lane j holds memory position j, and its cross-attn K/V per layer
    float m0 = mem[(b * S_ + lane) * DD_ + 0];
    float m1 = mem[(b * S_ + lane) * DD_ + 1];
    float m2 = mem[(b * S_ + lane) * DD_ + 2];

    float ck[NL_][3], cv[NL_][3];
    #pragma unroll
    for (int l = 0; l < NL_; ++l) {
        #pragma unroll
        for (int r = 0; r < 3; ++r) {
            ck[l][r] = wcq[l][3 + r][0] * m0 + wcq[l][3 + r][1] * m1 +
                       wcq[l][3 + r][2] * m2 + bcq[l][3 + r];
            cv[l][r] = wcq[l][6 + r][0] * m0 + wcq[l][6 + r][1] * m1 +
                       wcq[l][6 + r][2] * m2 + bcq[l][6 + r];
        }
    }

    // self-attn KV cache: lane j owns position j (zero-init to keep masked
    // lanes' speculative exp() finite)
    float sk[NL_][3] = {{0.f}}, sv[NL_][3] = {{0.f}};

    // tgt[:,0,:] = 0 (never overwritten by the scan)
    if (lane < 3) out[(b * S_ + 0) * 5 + lane] = 0.f;

    const float rs3 = 0.5773502691896258f;  // 1/sqrt(3)
    float y0 = 0.f, y1 = 0.f, y2 = 0.f;     // tgt[:, i]

    for (int i = 0; i < S_ - 1; ++i) {
        #pragma unroll
        for (int l = 0; l < NL_; ++l) {
            // ---- causal self-attention (incremental)
            float q[3], kn[3], vn[3];
            #pragma unroll
            for (int r = 0; r < 3; ++r) {
                q[r]  = wsq[l][r][0] * y0 + wsq[l][r][1] * y1 + wsq[l][r][2] * y2 + bsq[l][r];
                kn[r] = wsq[l][3 + r][0] * y0 + wsq[l][3 + r][1] * y1 + wsq[l][3 + r][2] * y2 + bsq[l][3 + r];
                vn[r] = wsq[l][6 + r][0] * y0 + wsq[l][6 + r][1] * y1 + wsq[l][6 + r][2] * y2 + bsq[l][6 + r];
            }
            if (lane == i) {
                #pragma unroll
                for (int r = 0; r < 3; ++r) { sk[l][r] = kn[r]; sv[l][r] = vn[r]; }
            }
            float sc = (q[0] * sk[l][0] + q[1] * sk[l][1] + q[2] * sk[l][2]) * rs3;
            float e = (lane <= i) ? expf(sc) : 0.f;
            float es  = wsum(e);
            float ev0 = wsum(e * sv[l][0]);
            float ev1 = wsum(e * sv[l][1]);
            float ev2 = wsum(e * sv[l][2]);
            float inv = 1.f / es;
            float a0 = ev0 * inv, a1 = ev1 * inv, a2 = ev2 * inv;
            float s0 = wso[l][0][0] * a0 + wso[l][0][1] * a1 + wso[l][0][2] * a2 + bso[l][0];
            float s1 = wso[l][1][0] * a0 + wso[l][1][1] * a1 + wso[l][1][2] * a2 + bso[l][1];
            float s2 = wso[l][2][0] * a0 + wso[l][2][1] * a1 + wso[l][2][2] * a2 + bso[l][2];
            ln3(y0 + s0, y1 + s1, y2 + s2, wn1[l], bn1[l], y0, y1, y2);

            // ---- cross-attention over memory (64 keys, all lanes active)
            float p0 = wcq[l][0][0] * y0 + wcq[l][0][1] * y1 + wcq[l][0][2] * y2 + bcq[l][0];
            float p1 = wcq[l][1][0] * y0 + wcq[l][1][1] * y1 + wcq[l][1][2] * y2 + bcq[l][1];
            float p2 = wcq[l][2][0] * y0 + wcq[l][2][1] * y1 + wcq[l][2][2] * y2 + bcq[l][2];
            float sc2 = (p0 * ck[l][0] + p1 * ck[l][1] + p2 * ck[l][2]) * rs3;
            float e2 = expf(sc2);
            float cs  = wsum(e2);
            float cv0 = wsum(e2 * cv[l][0]);
            float cv1 = wsum(e2 * cv[l][1]);
            float cv2 = wsum(e2 * cv[l][2]);
            inv = 1.f / cs;
            a0 = cv0 * inv; a1 = cv1 * inv; a2 = cv2 * inv;
            float c0 = wco[l][0][0] * a0 + wco[l][0][1] * a1 + wco[l][0][2] * a2 + bco[l][0];
            float c1 = wco[l][1][0] * a0 + wco[l][1][1] * a1 + wco[l][1][2] * a2 + bco[l][1];
            float c2 = wco[l][2][0] * a0 + wco[l][2][1] * a1 + wco[l][2][2] * a2 + bco[l][2];
            ln3(y0 + c0, y1 + c1, y2 + c2, wn2[l], bn2[l], y0, y1, y2);

            // ---- feed-forward 3 -> 4 -> 3 (relu)
            float h[4];
            #pragma unroll
            for (int f = 0; f < 4; ++f)
                h[f] = fmaxf(wf1[l][f][0] * y0 + wf1[l][f][1] * y1 + wf1[l][f][2] * y2 + bf1[l][f], 0.f);
            float f0 = wf2[l][0][0] * h[0] + wf2[l][0][1] * h[1] + wf2[l][0][2] * h[2] + wf2[l][0][3] * h[3] + bf2[l][0];
            float f1 = wf2[l][1][0] * h[0] + wf2[l][1][1] * h[1] + wf2[l][1][2] * h[2] + wf2[l][1][3] * h[3] + bf2[l][1];
            float f2 = wf2[l][2][0] * h[0] + wf2[l][2][1] * h[1] + wf2[l][2][2] * h[2] + wf2[l][2][3] * h[3] + bf2[l][2];
            ln3(y0 + f0, y1 + f1, y2 + f2, wn3[l], bn3[l], y0, y1, y2);
        }
        // tgt[:, i+1] = decode(tgt)[:, i]
        if (lane == 0) {
            out[(b * S_ + i + 1) * 5 + 0] = y0;
            out[(b * S_ + i + 1) * 5 + 1] = y1;
            out[(b * S_ + i + 1) * 5 + 2] = y2;
        }
        // y carries over: it IS tgt[:, i+1], the next step's input row
    }
}

// ---------------------------------------------------------------------------
extern "C" void kernel_launch(void* const* d_in, const int* in_sizes, int n_in,
                              void* d_out, int out_size, void* d_ws, size_t ws_size,
                              hipStream_t stream) {
    const float* src  = (const float*)d_in[0];
    const float* wemb = (const float*)d_in[1];
    const float* semb = (const float*)d_in[2];

    float* mem = (float*)d_ws;           // [B,S,3] scratch
    float* out = (float*)d_out;          // [B,S,5]

    enc_kernel<<<B_, 128, 0, stream>>>(
        src, wemb, semb,
        (const float*)d_in[3],  (const float*)d_in[4],
        (const float*)d_in[5],  (const float*)d_in[6],
        (const float*)d_in[7],  (const float*)d_in[8],
        (const float*)d_in[9],  (const float*)d_in[10],
        (const float*)d_in[11], (const float*)d_in[12],
        (const float*)d_in[13], (const float*)d_in[14],
        (const float*)d_in[15], (const float*)d_in[16],
        (const float*)d_in[17], (const float*)d_in[18],
        mem, out);

    dec_kernel<<<B_, 64, 0, stream>>>(
        mem,
        (const float*)d_in[19], (const float*)d_in[20],
        (const float*)d_in[21], (const float*)d_in[22],
        (const float*)d_in[23], (const float*)d_in[24],
        (const float*)d_in[25], (const float*)d_in[26],
        (const float*)d_in[27], (const float*)d_in[28],
        (const float*)d_in[29], (const float*)d_in[30],
        (const float*)d_in[31], (const float*)d_in[32],
        (const float*)d_in[33], (const float*)d_in[34],
        (const float*)d_in[35], (const float*)d_in[36],
        out);
}

// Round 3
// 567.194 us; speedup vs baseline: 1.1432x; 1.1432x over previous
//
#include <hip/hip_runtime.h>
#include <math.h>

#define B_ 64
#define S_ 64
#define U_ 16
#define EMB_ 10
#define D_ 34
#define DD_ 3
#define FF_ 4
#define NL_ 4

// ---------------------------------------------------------------------------
// Kernel A: embedding + pos-encoding quirk + 4 post-norm encoder layers +
// final LN + projection to memory[B,S,3] (stored in d_ws).
// One block per batch element, 256 threads (4 waves). Per-layer weights are
// staged into LDS with coalesced loads.
// ---------------------------------------------------------------------------
__global__ __launch_bounds__(256) void enc_kernel(
    const float* __restrict__ src, const float* __restrict__ wemb,
    const float* __restrict__ semb,
    const float* __restrict__ qkv_w, const float* __restrict__ qkv_b,
    const float* __restrict__ out_w, const float* __restrict__ out_b,
    const float* __restrict__ ln1_w, const float* __restrict__ ln1_b,
    const float* __restrict__ lin1_w, const float* __restrict__ lin1_b,
    const float* __restrict__ lin2_w, const float* __restrict__ lin2_b,
    const float* __restrict__ ln2_w, const float* __restrict__ ln2_b,
    const float* __restrict__ norm_w, const float* __restrict__ norm_b,
    const float* __restrict__ eo_w, const float* __restrict__ eo_b,
    float* __restrict__ mem, float* __restrict__ out)
{
    const int b = blockIdx.x;
    const int tid = threadIdx.x;

    __shared__ float xs[S_][D_ + 1];
    __shared__ float qs[S_][D_];
    __shared__ float ks[S_][D_];
    __shared__ float vs[S_][D_];
    __shared__ float att[S_][D_];
    __shared__ float ffh[S_][FF_];
    __shared__ float tmp[S_][D_ + 1];
    // per-layer weight staging
    __shared__ float wq_s[3 * D_ * D_];
    __shared__ float wo_s[D_ * D_];
    __shared__ float w1_s[FF_ * D_];
    __shared__ float w2_s[D_ * FF_];
    __shared__ float bq_s[3 * D_], bo_s[D_], b1_s[FF_], b2_s[D_];
    __shared__ float l1w_s[D_], l1b_s[D_], l2w_s[D_], l2b_s[D_];

    // ---- embed_lyrics + positional encoding (pe row b added to ALL positions)
    const float negln = -logf(10000.0f) / (float)D_;
    for (int idx = tid; idx < S_ * D_; idx += 256) {
        int pos = idx / D_, d = idx % D_;
        float v;
        if (d < U_ - 2) {
            v = src[(b * S_ + pos) * U_ + d];
        } else if (d < U_ - 2 + EMB_) {
            int wi = (int)src[(b * S_ + pos) * U_ + (U_ - 2)];
            v = wemb[wi * EMB_ + (d - (U_ - 2))];
        } else {
            int si = (int)src[(b * S_ + pos) * U_ + (U_ - 1)];
            v = semb[si * EMB_ + (d - (U_ - 2 + EMB_))];
        }
        int k = d >> 1;
        float div = expf((float)(2 * k) * negln);
        float ang = (float)b * div;
        v += (d & 1) ? cosf(ang) : sinf(ang);
        xs[pos][d] = v;
    }
    __syncthreads();

    const float rs17 = 0.24253562503633297f;  // 1/sqrt(17)

    for (int l = 0; l < NL_; ++l) {
        // ---- stage this layer's weights into LDS (coalesced)
        for (int t = tid; t < 3 * D_ * D_; t += 256) wq_s[t] = qkv_w[l * 3 * D_ * D_ + t];
        for (int t = tid; t < D_ * D_; t += 256)     wo_s[t] = out_w[l * D_ * D_ + t];
        for (int t = tid; t < FF_ * D_; t += 256)    w1_s[t] = lin1_w[l * FF_ * D_ + t];
        for (int t = tid; t < D_ * FF_; t += 256)    w2_s[t] = lin2_w[l * D_ * FF_ + t];
        // small vectors: concatenated range of 3D + 6*D + FF = 310 elements,
        // grid-stride loop so indices past 255 are covered (R2 bug: if-chain
        // referenced tids 256..305 that don't exist -> uninit LDS -> NaN)
        for (int t = tid; t < 3 * D_ + 6 * D_ + FF_; t += 256) {
            if      (t < 3 * D_)          bq_s[t]            = qkv_b[l * 3 * D_ + t];
            else if (t < 3 * D_ + D_)     bo_s[t - 3 * D_]   = out_b[l * D_ + (t - 3 * D_)];
            else if (t < 3 * D_ + 2 * D_) l1w_s[t - 4 * D_]  = ln1_w[l * D_ + (t - 4 * D_)];
            else if (t < 3 * D_ + 3 * D_) l1b_s[t - 5 * D_]  = ln1_b[l * D_ + (t - 5 * D_)];
            else if (t < 3 * D_ + 4 * D_) l2w_s[t - 6 * D_]  = ln2_w[l * D_ + (t - 6 * D_)];
            else if (t < 3 * D_ + 5 * D_) l2b_s[t - 7 * D_]  = ln2_b[l * D_ + (t - 7 * D_)];
            else if (t < 3 * D_ + 6 * D_) b2_s[t - 8 * D_]   = lin2_b[l * D_ + (t - 8 * D_)];
            else                          b1_s[t - 9 * D_]   = lin1_b[l * FF_ + (t - 9 * D_)];
        }
        __syncthreads();

        // ---- qkv projection
        for (int idx = tid; idx < S_ * 3 * D_; idx += 256) {
            int pos = idx / (3 * D_), r = idx % (3 * D_);
            const float* wrow = wq_s + r * D_;
            float acc = bq_s[r];
            #pragma unroll
            for (int d = 0; d < D_; ++d) acc += xs[pos][d] * wrow[d];
            if (r < D_)          qs[pos][r] = acc;
            else if (r < 2 * D_) ks[pos][r - D_] = acc;
            else                 vs[pos][r - 2 * D_] = acc;
        }
        __syncthreads();

        // ---- attention: thread = h*64 + qi (128 active); single-pass softmax
        if (tid < 128) {
            int h = tid >> 6, qi = tid & 63;
            int off = h * 17;
            float qv[17], acc[17];
            #pragma unroll
            for (int d = 0; d < 17; ++d) { qv[d] = qs[qi][off + d]; acc[d] = 0.f; }
            float ssum = 0.f;
            for (int j = 0; j < S_; ++j) {
                float sc = 0.f;
                #pragma unroll
                for (int d = 0; d < 17; ++d) sc += qv[d] * ks[j][off + d];
                float e = __expf(sc * rs17);
                ssum += e;
                #pragma unroll
                for (int d = 0; d < 17; ++d) acc[d] += e * vs[j][off + d];
            }
            float inv = 1.f / ssum;
            #pragma unroll
            for (int d = 0; d < 17; ++d) att[qi][off + d] = acc[d] * inv;
        }
        __syncthreads();

        // ---- out proj + residual
        for (int idx = tid; idx < S_ * D_; idx += 256) {
            int pos = idx / D_, d = idx % D_;
            const float* wrow = wo_s + d * D_;
            float acc = bo_s[d];
            #pragma unroll
            for (int e = 0; e < D_; ++e) acc += att[pos][e] * wrow[e];
            tmp[pos][d] = xs[pos][d] + acc;
        }
        __syncthreads();

        // ---- LN1
        if (tid < S_) {
            int row = tid;
            float mu = 0.f;
            for (int d = 0; d < D_; ++d) mu += tmp[row][d];
            mu *= (1.0f / D_);
            float var = 0.f;
            for (int d = 0; d < D_; ++d) { float t = tmp[row][d] - mu; var += t * t; }
            var *= (1.0f / D_);
            float rstd = rsqrtf(var + 1e-5f);
            for (int d = 0; d < D_; ++d)
                xs[row][d] = (tmp[row][d] - mu) * rstd * l1w_s[d] + l1b_s[d];
        }
        __syncthreads();

        // ---- FF1 (34 -> 4, relu)
        for (int idx = tid; idx < S_ * FF_; idx += 256) {
            int pos = idx / FF_, f = idx % FF_;
            const float* wrow = w1_s + f * D_;
            float acc = b1_s[f];
            #pragma unroll
            for (int d = 0; d < D_; ++d) acc += xs[pos][d] * wrow[d];
            ffh[pos][f] = fmaxf(acc, 0.f);
        }
        __syncthreads();

        // ---- FF2 (4 -> 34) + residual
        for (int idx = tid; idx < S_ * D_; idx += 256) {
            int pos = idx / D_, d = idx % D_;
            const float* wrow = w2_s + d * FF_;
            float acc = b2_s[d];
            #pragma unroll
            for (int f = 0; f < FF_; ++f) acc += ffh[pos][f] * wrow[f];
            tmp[pos][d] = xs[pos][d] + acc;
        }
        __syncthreads();

        // ---- LN2
        if (tid < S_) {
            int row = tid;
            float mu = 0.f;
            for (int d = 0; d < D_; ++d) mu += tmp[row][d];
            mu *= (1.0f / D_);
            float var = 0.f;
            for (int d = 0; d < D_; ++d) { float t = tmp[row][d] - mu; var += t * t; }
            var *= (1.0f / D_);
            float rstd = rsqrtf(var + 1e-5f);
            for (int d = 0; d < D_; ++d)
                xs[row][d] = (tmp[row][d] - mu) * rstd * l2w_s[d] + l2b_s[d];
        }
        __syncthreads();
    }

    // ---- final LayerNorm (norm_w/norm_b)
    if (tid < S_) {
        int row = tid;
        float mu = 0.f;
        for (int d = 0; d < D_; ++d) mu += xs[row][d];
        mu *= (1.0f / D_);
        float var = 0.f;
        for (int d = 0; d < D_; ++d) { float t = xs[row][d] - mu; var += t * t; }
        var *= (1.0f / D_);
        float rstd = rsqrtf(var + 1e-5f);
        for (int d = 0; d < D_; ++d)
            xs[row][d] = (xs[row][d] - mu) * rstd * norm_w[d] + norm_b[d];
    }
    __syncthreads();

    // ---- memory = x @ eo_w.T + eo_b  -> d_ws
    for (int idx = tid; idx < S_ * DD_; idx += 256) {
        int pos = idx / DD_, r = idx % DD_;
        const float* wrow = eo_w + r * D_;
        float acc = eo_b[r];
        #pragma unroll
        for (int d = 0; d < D_; ++d) acc += xs[pos][d] * wrow[d];
        mem[(b * S_ + pos) * DD_ + r] = acc;
    }

    // ---- pass-through output columns 3,4 (word / syllable idx)
    for (int pos = tid; pos < S_; pos += 256) {
        out[(b * S_ + pos) * 5 + 3] = src[(b * S_ + pos) * U_ + (U_ - 2)];
        out[(b * S_ + pos) * 5 + 4] = src[(b * S_ + pos) * U_ + (U_ - 1)];
    }
}

// ---------------------------------------------------------------------------
// Kernel B: incremental autoregressive decoder. One block = one wave = one
// batch element. Lane j owns position j's self-attn K/V and cross-attn K/V.
// 63 sequential steps. Softmax reductions via DPP (VALU pipe); chain-critical
// weights in registers (__launch_bounds__(64,1) -> 512-VGPR budget); native
// exp/rcp/rsq. No LDS.
// ---------------------------------------------------------------------------
template <int CTRL>
__device__ __forceinline__ float dpp_add(float v) {
    int t = __builtin_amdgcn_update_dpp(0, __float_as_int(v), CTRL, 0xf, 0xf, true);
    return v + __int_as_float(t);
}

// full-wave sum; valid in lane 63 only
__device__ __forceinline__ float wave_sum_l63(float v) {
    v = dpp_add<0x111>(v);  // row_shr:1
    v = dpp_add<0x112>(v);  // row_shr:2
    v = dpp_add<0x114>(v);  // row_shr:4
    v = dpp_add<0x118>(v);  // row_shr:8
    v = dpp_add<0x142>(v);  // row_bcast:15
    v = dpp_add<0x143>(v);  // row_bcast:31
    return v;
}

__device__ __forceinline__ float bcast63(float v) {
    return __int_as_float(__builtin_amdgcn_readlane(__float_as_int(v), 63));
}

__device__ __forceinline__ void ln3n(float z0, float z1, float z2,
                                     float w0, float w1, float w2,
                                     float b0, float b1, float b2,
                                     float& o0, float& o1, float& o2) {
    float mu = (z0 + z1 + z2) * (1.0f / 3.0f);
    float d0 = z0 - mu, d1 = z1 - mu, d2 = z2 - mu;
    float var = (d0 * d0 + d1 * d1 + d2 * d2) * (1.0f / 3.0f);
    float rstd = __builtin_amdgcn_rsqf(var + 1e-5f);
    o0 = d0 * rstd * w0 + b0;
    o1 = d1 * rstd * w1 + b1;
    o2 = d2 * rstd * w2 + b2;
}

__global__ __launch_bounds__(64, 1) void dec_kernel(
    const float* __restrict__ mem,
    const float* __restrict__ sa_qkv_w, const float* __restrict__ sa_qkv_b,
    const float* __restrict__ sa_out_w, const float* __restrict__ sa_out_b,
    const float* __restrict__ gln1_w, const float* __restrict__ gln1_b,
    const float* __restrict__ ca_qkv_w, const float* __restrict__ ca_qkv_b,
    const float* __restrict__ ca_out_w, const float* __restrict__ ca_out_b,
    const float* __restrict__ gln2_w, const float* __restrict__ gln2_b,
    const float* __restrict__ l1_w, const float* __restrict__ l1_b,
    const float* __restrict__ l2_w, const float* __restrict__ l2_b,
    const float* __restrict__ gln3_w, const float* __restrict__ gln3_b,
    float* __restrict__ out)
{
    const int b = blockIdx.x;
    const int lane = threadIdx.x;

    // ---- persistent register-resident weights (wave-uniform loads)
    float Wsq[NL_][9][3], Bsq[NL_][9];
    float Wso[NL_][3][3], Bso[NL_][3];
    float N1w[NL_][3], N1b[NL_][3];
    float Wcq[NL_][3][3], Bcq[NL_][3];
    float Wco[NL_][3][3], Bco[NL_][3];
    float N2w[NL_][3], N2b[NL_][3];

    #pragma unroll
    for (int l = 0; l < NL_; ++l) {
        #pragma unroll
        for (int r = 0; r < 9; ++r) {
            Bsq[l][r] = sa_qkv_b[l * 9 + r];
            #pragma unroll
            for (int c = 0; c < 3; ++c) Wsq[l][r][c] = sa_qkv_w[l * 27 + r * 3 + c];
        }
        #pragma unroll
        for (int r = 0; r < 3; ++r) {
            Bso[l][r] = sa_out_b[l * 3 + r];
            Bcq[l][r] = ca_qkv_b[l * 9 + r];
            Bco[l][r] = ca_out_b[l * 3 + r];
            N1w[l][r] = gln1_w[l * 3 + r];  N1b[l][r] = gln1_b[l * 3 + r];
            N2w[l][r] = gln2_w[l * 3 + r];  N2b[l][r] = gln2_b[l * 3 + r];
            #pragma unroll
            for (int c = 0; c < 3; ++c) {
                Wso[l][r][c] = sa_out_w[l * 9 + r * 3 + c];
                Wcq[l][r][c] = ca_qkv_w[l * 27 + r * 3 + c];
                Wco[l][r][c] = ca_out_w[l * 9 + r * 3 + c];
            }
        }
    }

    // ---- cross-attn K/V per lane (memory position = lane)
    float m0 = mem[(b * S_ + lane) * DD_ + 0];
    float m1 = mem[(b * S_ + lane) * DD_ + 1];
    float m2 = mem[(b * S_ + lane) * DD_ + 2];

    float ck[NL_][3], cv[NL_][3];
    #pragma unroll
    for (int l = 0; l < NL_; ++l) {
        #pragma unroll
        for (int r = 0; r < 3; ++r) {
            ck[l][r] = ca_qkv_w[l * 27 + (3 + r) * 3 + 0] * m0 +
                       ca_qkv_w[l * 27 + (3 + r) * 3 + 1] * m1 +
                       ca_qkv_w[l * 27 + (3 + r) * 3 + 2] * m2 + ca_qkv_b[l * 9 + 3 + r];
            cv[l][r] = ca_qkv_w[l * 27 + (6 + r) * 3 + 0] * m0 +
                       ca_qkv_w[l * 27 + (6 + r) * 3 + 1] * m1 +
                       ca_qkv_w[l * 27 + (6 + r) * 3 + 2] * m2 + ca_qkv_b[l * 9 + 6 + r];
        }
    }

    // self-attn KV cache: lane j owns position j
    float sk[NL_][3] = {{0.f}}, sv[NL_][3] = {{0.f}};

    // tgt[:,0,:] = 0 (never overwritten by the scan)
    if (lane < 3) out[(b * S_ + 0) * 5 + lane] = 0.f;

    const float rs3 = 0.5773502691896258f;  // 1/sqrt(3)
    float y0 = 0.f, y1 = 0.f, y2 = 0.f;

    for (int i = 0; i < S_ - 1; ++i) {
        #pragma unroll
        for (int l = 0; l < NL_; ++l) {
            // transient weights for the tail of the layer: wave-uniform scalar
            // loads, issued early so the latency hides under attention work
            float F1w[4][3], F1b[4], F2w[3][4], F2b[3], N3w[3], N3b[3];
            #pragma unroll
            for (int f = 0; f < 4; ++f) {
                F1b[f] = l1_b[l * 4 + f];
                #pragma unroll
                for (int c = 0; c < 3; ++c) F1w[f][c] = l1_w[l * 12 + f * 3 + c];
            }
            #pragma unroll
            for (int r = 0; r < 3; ++r) {
                F2b[r] = l2_b[l * 3 + r];
                N3w[r] = gln3_w[l * 3 + r];  N3b[r] = gln3_b[l * 3 + r];
                #pragma unroll
                for (int c = 0; c < 4; ++c) F2w[r][c] = l2_w[l * 12 + r * 4 + c];
            }

            // ---- causal self-attention (incremental)
            float q[3], kn[3], vn[3];
            #pragma unroll
            for (int r = 0; r < 3; ++r) {
                q[r]  = Wsq[l][r][0] * y0 + Wsq[l][r][1] * y1 + Wsq[l][r][2] * y2 + Bsq[l][r];
                kn[r] = Wsq[l][3 + r][0] * y0 + Wsq[l][3 + r][1] * y1 + Wsq[l][3 + r][2] * y2 + Bsq[l][3 + r];
                vn[r] = Wsq[l][6 + r][0] * y0 + Wsq[l][6 + r][1] * y1 + Wsq[l][6 + r][2] * y2 + Bsq[l][6 + r];
            }
            if (lane == i) {
                #pragma unroll
                for (int r = 0; r < 3; ++r) { sk[l][r] = kn[r]; sv[l][r] = vn[r]; }
            }
            float sc = (q[0] * sk[l][0] + q[1] * sk[l][1] + q[2] * sk[l][2]) * rs3;
            float e = (lane <= i) ? __expf(sc) : 0.f;
            float es  = wave_sum_l63(e);
            float ev0 = wave_sum_l63(e * sv[l][0]);
            float ev1 = wave_sum_l63(e * sv[l][1]);
            float ev2 = wave_sum_l63(e * sv[l][2]);
            float inv = __builtin_amdgcn_rcpf(bcast63(es));
            float a0 = bcast63(ev0) * inv, a1 = bcast63(ev1) * inv, a2 = bcast63(ev2) * inv;
            float s0 = Wso[l][0][0] * a0 + Wso[l][0][1] * a1 + Wso[l][0][2] * a2 + Bso[l][0];
            float s1 = Wso[l][1][0] * a0 + Wso[l][1][1] * a1 + Wso[l][1][2] * a2 + Bso[l][1];
            float s2 = Wso[l][2][0] * a0 + Wso[l][2][1] * a1 + Wso[l][2][2] * a2 + Bso[l][2];
            ln3n(y0 + s0, y1 + s1, y2 + s2,
                 N1w[l][0], N1w[l][1], N1w[l][2], N1b[l][0], N1b[l][1], N1b[l][2],
                 y0, y1, y2);

            // ---- cross-attention over memory (64 keys)
            float p0 = Wcq[l][0][0] * y0 + Wcq[l][0][1] * y1 + Wcq[l][0][2] * y2 + Bcq[l][0];
            float p1 = Wcq[l][1][0] * y0 + Wcq[l][1][1] * y1 + Wcq[l][1][2] * y2 + Bcq[l][1];
            float p2 = Wcq[l][2][0] * y0 + Wcq[l][2][1] * y1 + Wcq[l][2][2] * y2 + Bcq[l][2];
            float sc2 = (p0 * ck[l][0] + p1 * ck[l][1] + p2 * ck[l][2]) * rs3;
            float e2 = __expf(sc2);
            float cs  = wave_sum_l63(e2);
            float cw0 = wave_sum_l63(e2 * cv[l][0]);
            float cw1 = wave_sum_l63(e2 * cv[l][1]);
            float cw2 = wave_sum_l63(e2 * cv[l][2]);
            inv = __builtin_amdgcn_rcpf(bcast63(cs));
            a0 = bcast63(cw0) * inv; a1 = bcast63(cw1) * inv; a2 = bcast63(cw2) * inv;
            float c0 = Wco[l][0][0] * a0 + Wco[l][0][1] * a1 + Wco[l][0][2] * a2 + Bco[l][0];
            float c1 = Wco[l][1][0] * a0 + Wco[l][1][1] * a1 + Wco[l][1][2] * a2 + Bco[l][1];
            float c2 = Wco[l][2][0] * a0 + Wco[l][2][1] * a1 + Wco[l][2][2] * a2 + Bco[l][2];
            ln3n(y0 + c0, y1 + c1, y2 + c2,
                 N2w[l][0], N2w[l][1], N2w[l][2], N2b[l][0], N2b[l][1], N2b[l][2],
                 y0, y1, y2);

            // ---- feed-forward 3 -> 4 -> 3 (relu)
            float h[4];
            #pragma unroll
            for (int f = 0; f < 4; ++f)
                h[f] = fmaxf(F1w[f][0] * y0 + F1w[f][1] * y1 + F1w[f][2] * y2 + F1b[f], 0.f);
            float f0 = F2w[0][0] * h[0] + F2w[0][1] * h[1] + F2w[0][2] * h[2] + F2w[0][3] * h[3] + F2b[0];
            float f1 = F2w[1][0] * h[0] + F2w[1][1] * h[1] + F2w[1][2] * h[2] + F2w[1][3] * h[3] + F2b[1];
            float f2 = F2w[2][0] * h[0] + F2w[2][1] * h[1] + F2w[2][2] * h[2] + F2w[2][3] * h[3] + F2b[2];
            ln3n(y0 + f0, y1 + f1, y2 + f2,
                 N3w[0], N3w[1], N3w[2], N3b[0], N3b[1], N3b[2],
                 y0, y1, y2);
        }
        // tgt[:, i+1] = decode(tgt)[:, i]
        if (lane == 0) {
            out[(b * S_ + i + 1) * 5 + 0] = y0;
            out[(b * S_ + i + 1) * 5 + 1] = y1;
            out[(b * S_ + i + 1) * 5 + 2] = y2;
        }
    }
}

// ---------------------------------------------------------------------------
extern "C" void kernel_launch(void* const* d_in, const int* in_sizes, int n_in,
                              void* d_out, int out_size, void* d_ws, size_t ws_size,
                              hipStream_t stream) {
    const float* src  = (const float*)d_in[0];
    const float* wemb = (const float*)d_in[1];
    const float* semb = (const float*)d_in[2];

    float* mem = (float*)d_ws;           // [B,S,3] scratch
    float* out = (float*)d_out;          // [B,S,5]

    enc_kernel<<<B_, 256, 0, stream>>>(
        src, wemb, semb,
        (const float*)d_in[3],  (const float*)d_in[4],
        (const float*)d_in[5],  (const float*)d_in[6],
        (const float*)d_in[7],  (const float*)d_in[8],
        (const float*)d_in[9],  (const float*)d_in[10],
        (const float*)d_in[11], (const float*)d_in[12],
        (const float*)d_in[13], (const float*)d_in[14],
        (const float*)d_in[15], (const float*)d_in[16],
        (const float*)d_in[17], (const float*)d_in[18],
        mem, out);

    dec_kernel<<<B_, 64, 0, stream>>>(
        mem,
        (const float*)d_in[19], (const float*)d_in[20],
        (const float*)d_in[21], (const float*)d_in[22],
        (const float*)d_in[23], (const float*)d_in[24],
        (const float*)d_in[25], (const float*)d_in[26],
        (const float*)d_in[27], (const float*)d_in[28],
        (const float*)d_in[29], (const float*)d_in[30],
        (const float*)d_in[31], (const float*)d_in[32],
        (const float*)d_in[33], (const float*)d_in[34],
        (const float*)d_in[35], (const float*)d_in[36],
        out);
}

// Round 4
// 417.116 us; speedup vs baseline: 1.5545x; 1.3598x over previous
//
#include <hip/hip_runtime.h>
#include <math.h>

#define B_ 64
#define S_ 64
#define U_ 16
#define EMB_ 10
#define D_ 34
#define DD_ 3
#define FF_ 4
#define NL_ 4

// ---------------------------------------------------------------------------
// Kernel A: embedding + pos-encoding quirk + 4 post-norm encoder layers +
// final LN + projection to memory[B,S,3] (stored in d_ws).
// One block per batch element, 256 threads (4 waves, 1/SIMD). Weights staged
// in LDS. All hot loops: fixed trip count, fully/partially unrolled, split
// accumulators for ILP (1 wave/SIMD -> latency must hide inside the wave).
// Activation arrays have pad rows so rep-loops need no bounds checks; pad
// rows may hold garbage/NaN but are never read into live results.
// ---------------------------------------------------------------------------
__global__ __launch_bounds__(256) void enc_kernel(
    const float* __restrict__ src, const float* __restrict__ wemb,
    const float* __restrict__ semb,
    const float* __restrict__ qkv_w, const float* __restrict__ qkv_b,
    const float* __restrict__ out_w, const float* __restrict__ out_b,
    const float* __restrict__ ln1_w, const float* __restrict__ ln1_b,
    const float* __restrict__ lin1_w, const float* __restrict__ lin1_b,
    const float* __restrict__ lin2_w, const float* __restrict__ lin2_b,
    const float* __restrict__ ln2_w, const float* __restrict__ ln2_b,
    const float* __restrict__ norm_w, const float* __restrict__ norm_b,
    const float* __restrict__ eo_w, const float* __restrict__ eo_b,
    float* __restrict__ mem, float* __restrict__ out)
{
    const int b = blockIdx.x;
    const int tid = threadIdx.x;

    __shared__ float xs[S_ + 4][D_ + 1];   // read rows <= 67 by out-proj/FF2
    __shared__ float qs[S_ + 2][D_];       // written rows <= 65 by qkv
    __shared__ float ks[S_ + 2][D_];
    __shared__ float vs[S_ + 2][D_];
    __shared__ float att[S_ + 4][D_];      // read rows <= 67 by out-proj
    __shared__ float ffh[S_ + 4][FF_];     // read rows <= 67 by FF2
    __shared__ float tmp[S_ + 4][D_ + 1];  // written rows <= 67
    // per-layer weight staging
    __shared__ float wq_s[3 * D_ * D_];
    __shared__ float wo_s[D_ * D_];
    __shared__ float w1_s[FF_ * D_];
    __shared__ float w2_s[D_ * FF_];
    __shared__ float bq_s[3 * D_], bo_s[D_], b1_s[FF_], b2_s[D_];
    __shared__ float l1w_s[D_], l1b_s[D_], l2w_s[D_], l2b_s[D_];

    // ---- embed_lyrics + positional encoding (pe row b added to ALL positions)
    const float negln = -logf(10000.0f) / (float)D_;
    #pragma unroll 2
    for (int rep = 0; rep < 9; ++rep) {           // 9*256 = 2304 >= 2176
        int idx = tid + rep * 256;
        int pos = idx / D_;  if (pos > S_ - 1) pos = S_ - 1;  // clamp: dup same-value writes
        int d = idx % D_;
        float v;
        if (d < U_ - 2) {
            v = src[(b * S_ + pos) * U_ + d];
        } else if (d < U_ - 2 + EMB_) {
            int wi = (int)src[(b * S_ + pos) * U_ + (U_ - 2)];
            v = wemb[wi * EMB_ + (d - (U_ - 2))];
        } else {
            int si = (int)src[(b * S_ + pos) * U_ + (U_ - 1)];
            v = semb[si * EMB_ + (d - (U_ - 2 + EMB_))];
        }
        int k = d >> 1;
        float div = expf((float)(2 * k) * negln);
        float ang = (float)b * div;
        v += (d & 1) ? cosf(ang) : sinf(ang);
        xs[pos][d] = v;
    }
    __syncthreads();

    const float rs17 = 0.24253562503633297f;  // 1/sqrt(17)

    for (int l = 0; l < NL_; ++l) {
        // ---- stage this layer's weights into LDS (coalesced)
        for (int t = tid; t < 3 * D_ * D_; t += 256) wq_s[t] = qkv_w[l * 3 * D_ * D_ + t];
        for (int t = tid; t < D_ * D_; t += 256)     wo_s[t] = out_w[l * D_ * D_ + t];
        for (int t = tid; t < FF_ * D_; t += 256)    w1_s[t] = lin1_w[l * FF_ * D_ + t];
        for (int t = tid; t < D_ * FF_; t += 256)    w2_s[t] = lin2_w[l * D_ * FF_ + t];
        for (int t = tid; t < 3 * D_ + 6 * D_ + FF_; t += 256) {
            if      (t < 3 * D_)          bq_s[t]            = qkv_b[l * 3 * D_ + t];
            else if (t < 3 * D_ + D_)     bo_s[t - 3 * D_]   = out_b[l * D_ + (t - 3 * D_)];
            else if (t < 3 * D_ + 2 * D_) l1w_s[t - 4 * D_]  = ln1_w[l * D_ + (t - 4 * D_)];
            else if (t < 3 * D_ + 3 * D_) l1b_s[t - 5 * D_]  = ln1_b[l * D_ + (t - 5 * D_)];
            else if (t < 3 * D_ + 4 * D_) l2w_s[t - 6 * D_]  = ln2_w[l * D_ + (t - 6 * D_)];
            else if (t < 3 * D_ + 5 * D_) l2b_s[t - 7 * D_]  = ln2_b[l * D_ + (t - 7 * D_)];
            else if (t < 3 * D_ + 6 * D_) b2_s[t - 8 * D_]   = lin2_b[l * D_ + (t - 8 * D_)];
            else                          b1_s[t - 9 * D_]   = lin1_b[l * FF_ + (t - 9 * D_)];
        }
        __syncthreads();

        // ---- qkv projection: 26*256 = 6656 >= 6528 outputs (pad rows absorb)
        #pragma unroll 4
        for (int rep = 0; rep < 26; ++rep) {
            int idx = tid + rep * 256;
            int pos = idx / (3 * D_), r = idx % (3 * D_);
            const float* wrow = wq_s + r * D_;
            float aE = bq_s[r], aO = 0.f;
            #pragma unroll
            for (int d = 0; d < D_; d += 2) {
                aE += xs[pos][d] * wrow[d];
                aO += xs[pos][d + 1] * wrow[d + 1];
            }
            float acc = aE + aO;
            if (r < D_)          qs[pos][r] = acc;
            else if (r < 2 * D_) ks[pos][r - D_] = acc;
            else                 vs[pos][r - 2 * D_] = acc;
        }
        __syncthreads();

        // ---- attention: thread = h*64 + qi (128 active); single-pass softmax
        if (tid < 128) {
            int h = tid >> 6, qi = tid & 63;
            int off = h * 17;
            float qv[17], acc[17];
            #pragma unroll
            for (int d = 0; d < 17; ++d) { qv[d] = qs[qi][off + d]; acc[d] = 0.f; }
            float ssum = 0.f;
            #pragma unroll 2
            for (int j = 0; j < S_; ++j) {
                float sE = 0.f, sO = 0.f;
                #pragma unroll
                for (int d = 0; d < 16; d += 2) {
                    sE += qv[d] * ks[j][off + d];
                    sO += qv[d + 1] * ks[j][off + d + 1];
                }
                float sc = sE + sO + qv[16] * ks[j][off + 16];
                float e = __expf(sc * rs17);
                ssum += e;
                #pragma unroll
                for (int d = 0; d < 17; ++d) acc[d] += e * vs[j][off + d];
            }
            float inv = 1.f / ssum;
            #pragma unroll
            for (int d = 0; d < 17; ++d) att[qi][off + d] = acc[d] * inv;
        }
        __syncthreads();

        // ---- out proj + residual: 9*256 = 2304 >= 2176
        #pragma unroll 3
        for (int rep = 0; rep < 9; ++rep) {
            int idx = tid + rep * 256;
            int pos = idx / D_, d = idx % D_;
            const float* wrow = wo_s + d * D_;
            float aE = bo_s[d], aO = 0.f;
            #pragma unroll
            for (int e = 0; e < D_; e += 2) {
                aE += att[pos][e] * wrow[e];
                aO += att[pos][e + 1] * wrow[e + 1];
            }
            tmp[pos][d] = xs[pos][d] + aE + aO;
        }
        __syncthreads();

        // ---- LN1
        if (tid < S_) {
            int row = tid;
            float sA = 0.f, sB = 0.f;
            #pragma unroll
            for (int d = 0; d < D_; d += 2) { sA += tmp[row][d]; sB += tmp[row][d + 1]; }
            float mu = (sA + sB) * (1.0f / D_);
            float vA = 0.f, vB = 0.f;
            #pragma unroll
            for (int d = 0; d < D_; d += 2) {
                float t0 = tmp[row][d] - mu;     vA += t0 * t0;
                float t1 = tmp[row][d + 1] - mu; vB += t1 * t1;
            }
            float rstd = rsqrtf((vA + vB) * (1.0f / D_) + 1e-5f);
            #pragma unroll
            for (int d = 0; d < D_; ++d)
                xs[row][d] = (tmp[row][d] - mu) * rstd * l1w_s[d] + l1b_s[d];
        }
        __syncthreads();

        // ---- FF1 (34 -> 4, relu): exactly 256 outputs
        {
            int pos = tid >> 2, f = tid & 3;
            const float* wrow = w1_s + f * D_;
            float aE = b1_s[f], aO = 0.f;
            #pragma unroll
            for (int d = 0; d < D_; d += 2) {
                aE += xs[pos][d] * wrow[d];
                aO += xs[pos][d + 1] * wrow[d + 1];
            }
            ffh[pos][f] = fmaxf(aE + aO, 0.f);
        }
        __syncthreads();

        // ---- FF2 (4 -> 34) + residual: 9*256 >= 2176
        #pragma unroll 3
        for (int rep = 0; rep < 9; ++rep) {
            int idx = tid + rep * 256;
            int pos = idx / D_, d = idx % D_;
            const float* wrow = w2_s + d * FF_;
            float acc = b2_s[d] + ffh[pos][0] * wrow[0] + ffh[pos][1] * wrow[1] +
                        ffh[pos][2] * wrow[2] + ffh[pos][3] * wrow[3];
            tmp[pos][d] = xs[pos][d] + acc;
        }
        __syncthreads();

        // ---- LN2
        if (tid < S_) {
            int row = tid;
            float sA = 0.f, sB = 0.f;
            #pragma unroll
            for (int d = 0; d < D_; d += 2) { sA += tmp[row][d]; sB += tmp[row][d + 1]; }
            float mu = (sA + sB) * (1.0f / D_);
            float vA = 0.f, vB = 0.f;
            #pragma unroll
            for (int d = 0; d < D_; d += 2) {
                float t0 = tmp[row][d] - mu;     vA += t0 * t0;
                float t1 = tmp[row][d + 1] - mu; vB += t1 * t1;
            }
            float rstd = rsqrtf((vA + vB) * (1.0f / D_) + 1e-5f);
            #pragma unroll
            for (int d = 0; d < D_; ++d)
                xs[row][d] = (tmp[row][d] - mu) * rstd * l2w_s[d] + l2b_s[d];
        }
        __syncthreads();
    }

    // ---- final LayerNorm (norm_w/norm_b)
    if (tid < S_) {
        int row = tid;
        float sA = 0.f, sB = 0.f;
        #pragma unroll
        for (int d = 0; d < D_; d += 2) { sA += xs[row][d]; sB += xs[row][d + 1]; }
        float mu = (sA + sB) * (1.0f / D_);
        float vA = 0.f, vB = 0.f;
        #pragma unroll
        for (int d = 0; d < D_; d += 2) {
            float t0 = xs[row][d] - mu;     vA += t0 * t0;
            float t1 = xs[row][d + 1] - mu; vB += t1 * t1;
        }
        float rstd = rsqrtf((vA + vB) * (1.0f / D_) + 1e-5f);
        #pragma unroll
        for (int d = 0; d < D_; ++d)
            xs[row][d] = (xs[row][d] - mu) * rstd * norm_w[d] + norm_b[d];
    }
    __syncthreads();

    // ---- memory = x @ eo_w.T + eo_b  -> d_ws (192 outputs)
    if (tid < S_ * DD_) {
        int pos = tid / DD_, r = tid % DD_;
        const float* wrow = eo_w + r * D_;
        float aE = eo_b[r], aO = 0.f;
        #pragma unroll
        for (int d = 0; d < D_; d += 2) {
            aE += xs[pos][d] * wrow[d];
            aO += xs[pos][d + 1] * wrow[d + 1];
        }
        mem[(b * S_ + pos) * DD_ + r] = aE + aO;
    }

    // ---- pass-through output columns 3,4 (word / syllable idx)
    for (int pos = tid; pos < S_; pos += 256) {
        out[(b * S_ + pos) * 5 + 3] = src[(b * S_ + pos) * U_ + (U_ - 2)];
        out[(b * S_ + pos) * 5 + 4] = src[(b * S_ + pos) * U_ + (U_ - 1)];
    }
}

// ---------------------------------------------------------------------------
// Kernel B: incremental autoregressive decoder. One block = one wave = one
// batch element. Lane j owns position j's self/cross K/V. DPP softmax sums.
// Chain-critical weights PINNED into VGPRs via opaque asm — R3 showed the
// compiler demotes wave-uniform loads to SGPR + per-iteration s_load re-
// materialization, and s_load forces lgkmcnt(0) full drains on the serial
// chain (VGPR_Count was 40!). The asm result is not provably uniform, so it
// must stay in a VGPR for the kernel's lifetime.
// ---------------------------------------------------------------------------
#define PIN(x) asm volatile("" : "+v"(x))

template <int CTRL>
__device__ __forceinline__ float dpp_add(float v) {
    int t = __builtin_amdgcn_update_dpp(0, __float_as_int(v), CTRL, 0xf, 0xf, true);
    return v + __int_as_float(t);
}

// full-wave sum; valid in lane 63 only
__device__ __forceinline__ float wave_sum_l63(float v) {
    v = dpp_add<0x111>(v);  // row_shr:1
    v = dpp_add<0x112>(v);  // row_shr:2
    v = dpp_add<0x114>(v);  // row_shr:4
    v = dpp_add<0x118>(v);  // row_shr:8
    v = dpp_add<0x142>(v);  // row_bcast:15
    v = dpp_add<0x143>(v);  // row_bcast:31
    return v;
}

__device__ __forceinline__ float bcast63(float v) {
    return __int_as_float(__builtin_amdgcn_readlane(__float_as_int(v), 63));
}

__device__ __forceinline__ void ln3n(float z0, float z1, float z2,
                                     float w0, float w1, float w2,
                                     float b0, float b1, float b2,
                                     float& o0, float& o1, float& o2) {
    float mu = (z0 + z1 + z2) * (1.0f / 3.0f);
    float d0 = z0 - mu, d1 = z1 - mu, d2 = z2 - mu;
    float var = (d0 * d0 + d1 * d1 + d2 * d2) * (1.0f / 3.0f);
    float rstd = __builtin_amdgcn_rsqf(var + 1e-5f);
    o0 = d0 * rstd * w0 + b0;
    o1 = d1 * rstd * w1 + b1;
    o2 = d2 * rstd * w2 + b2;
}

__global__ __launch_bounds__(64, 1) void dec_kernel(
    const float* __restrict__ mem,
    const float* __restrict__ sa_qkv_w, const float* __restrict__ sa_qkv_b,
    const float* __restrict__ sa_out_w, const float* __restrict__ sa_out_b,
    const float* __restrict__ gln1_w, const float* __restrict__ gln1_b,
    const float* __restrict__ ca_qkv_w, const float* __restrict__ ca_qkv_b,
    const float* __restrict__ ca_out_w, const float* __restrict__ ca_out_b,
    const float* __restrict__ gln2_w, const float* __restrict__ gln2_b,
    const float* __restrict__ l1_w, const float* __restrict__ l1_b,
    const float* __restrict__ l2_w, const float* __restrict__ l2_b,
    const float* __restrict__ gln3_w, const float* __restrict__ gln3_b,
    float* __restrict__ out)
{
    const int b = blockIdx.x;
    const int lane = threadIdx.x;

    // ---- persistent weights (loaded once, then pinned to VGPRs)
    float Wsq[NL_][9][3], Bsq[NL_][9];
    float Wso[NL_][3][3], Bso[NL_][3];
    float N1w[NL_][3], N1b[NL_][3];
    float Wcq[NL_][3][3], Bcq[NL_][3];
    float Wco[NL_][3][3], Bco[NL_][3];
    float N2w[NL_][3], N2b[NL_][3];
    float F1w[NL_][4][3], F1b[NL_][4];
    // compiler-managed (SGPR-resident or re-loaded; one drain point/segment
    // with ~300cy of slack): FF2 + LN3
    float F2w[NL_][3][4], F2b[NL_][3], N3w[NL_][3], N3b[NL_][3];

    #pragma unroll
    for (int l = 0; l < NL_; ++l) {
        #pragma unroll
        for (int r = 0; r < 9; ++r) {
            Bsq[l][r] = sa_qkv_b[l * 9 + r];
            #pragma unroll
            for (int c = 0; c < 3; ++c) Wsq[l][r][c] = sa_qkv_w[l * 27 + r * 3 + c];
        }
        #pragma unroll
        for (int r = 0; r < 3; ++r) {
            Bso[l][r] = sa_out_b[l * 3 + r];
            Bcq[l][r] = ca_qkv_b[l * 9 + r];
            Bco[l][r] = ca_out_b[l * 3 + r];
            N1w[l][r] = gln1_w[l * 3 + r];  N1b[l][r] = gln1_b[l * 3 + r];
            N2w[l][r] = gln2_w[l * 3 + r];  N2b[l][r] = gln2_b[l * 3 + r];
            N3w[l][r] = gln3_w[l * 3 + r];  N3b[l][r] = gln3_b[l * 3 + r];
            F2b[l][r] = l2_b[l * 3 + r];
            #pragma unroll
            for (int c = 0; c < 3; ++c) {
                Wso[l][r][c] = sa_out_w[l * 9 + r * 3 + c];
                Wcq[l][r][c] = ca_qkv_w[l * 27 + r * 3 + c];
                Wco[l][r][c] = ca_out_w[l * 9 + r * 3 + c];
            }
            #pragma unroll
            for (int c = 0; c < 4; ++c) F2w[l][r][c] = l2_w[l * 12 + r * 4 + c];
        }
        #pragma unroll
        for (int f = 0; f < 4; ++f) {
            F1b[l][f] = l1_b[l * 4 + f];
            #pragma unroll
            for (int c = 0; c < 3; ++c) F1w[l][f][c] = l1_w[l * 12 + f * 3 + c];
        }
    }

    // ---- cross-attn K/V per lane (memory position = lane)
    float m0 = mem[(b * S_ + lane) * DD_ + 0];
    float m1 = mem[(b * S_ + lane) * DD_ + 1];
    float m2 = mem[(b * S_ + lane) * DD_ + 2];

    float ck[NL_][3], cv[NL_][3];
    #pragma unroll
    for (int l = 0; l < NL_; ++l) {
        #pragma unroll
        for (int r = 0; r < 3; ++r) {
            ck[l][r] = ca_qkv_w[l * 27 + (3 + r) * 3 + 0] * m0 +
                       ca_qkv_w[l * 27 + (3 + r) * 3 + 1] * m1 +
                       ca_qkv_w[l * 27 + (3 + r) * 3 + 2] * m2 + ca_qkv_b[l * 9 + 3 + r];
            cv[l][r] = ca_qkv_w[l * 27 + (6 + r) * 3 + 0] * m0 +
                       ca_qkv_w[l * 27 + (6 + r) * 3 + 1] * m1 +
                       ca_qkv_w[l * 27 + (6 + r) * 3 + 2] * m2 + ca_qkv_b[l * 9 + 6 + r];
        }
    }

    // ---- pin the chain-critical set into VGPRs (~400 regs; budget 512)
    #pragma unroll
    for (int l = 0; l < NL_; ++l) {
        #pragma unroll
        for (int r = 0; r < 9; ++r) {
            PIN(Bsq[l][r]);
            #pragma unroll
            for (int c = 0; c < 3; ++c) PIN(Wsq[l][r][c]);
        }
        #pragma unroll
        for (int r = 0; r < 3; ++r) {
            PIN(Bso[l][r]); PIN(Bcq[l][r]); PIN(Bco[l][r]);
            PIN(N1w[l][r]); PIN(N1b[l][r]); PIN(N2w[l][r]); PIN(N2b[l][r]);
            #pragma unroll
            for (int c = 0; c < 3; ++c) { PIN(Wso[l][r][c]); PIN(Wcq[l][r][c]); PIN(Wco[l][r][c]); }
        }
        #pragma unroll
        for (int f = 0; f < 4; ++f) {
            PIN(F1b[l][f]);
            #pragma unroll
            for (int c = 0; c < 3; ++c) PIN(F1w[l][f][c]);
        }
    }

    // self-attn KV cache: lane j owns position j
    float sk[NL_][3] = {{0.f}}, sv[NL_][3] = {{0.f}};

    // tgt[:,0,:] = 0 (never overwritten by the scan)
    if (lane < 3) out[(b * S_ + 0) * 5 + lane] = 0.f;

    const float rs3 = 0.5773502691896258f;  // 1/sqrt(3)
    float y0 = 0.f, y1 = 0.f, y2 = 0.f;

    for (int i = 0; i < S_ - 1; ++i) {
        #pragma unroll
        for (int l = 0; l < NL_; ++l) {
            // ---- causal self-attention (incremental)
            float q[3], kn[3], vn[3];
            #pragma unroll
            for (int r = 0; r < 3; ++r) {
                q[r]  = Wsq[l][r][0] * y0 + Wsq[l][r][1] * y1 + Wsq[l][r][2] * y2 + Bsq[l][r];
                kn[r] = Wsq[l][3 + r][0] * y0 + Wsq[l][3 + r][1] * y1 + Wsq[l][3 + r][2] * y2 + Bsq[l][3 + r];
                vn[r] = Wsq[l][6 + r][0] * y0 + Wsq[l][6 + r][1] * y1 + Wsq[l][6 + r][2] * y2 + Bsq[l][6 + r];
            }
            if (lane == i) {
                #pragma unroll
                for (int r = 0; r < 3; ++r) { sk[l][r] = kn[r]; sv[l][r] = vn[r]; }
            }
            float sc = (q[0] * sk[l][0] + q[1] * sk[l][1] + q[2] * sk[l][2]) * rs3;
            float e = (lane <= i) ? __expf(sc) : 0.f;
            float es  = wave_sum_l63(e);
            float ev0 = wave_sum_l63(e * sv[l][0]);
            float ev1 = wave_sum_l63(e * sv[l][1]);
            float ev2 = wave_sum_l63(e * sv[l][2]);
            float inv = __builtin_amdgcn_rcpf(bcast63(es));
            float a0 = bcast63(ev0) * inv, a1 = bcast63(ev1) * inv, a2 = bcast63(ev2) * inv;
            float s0 = Wso[l][0][0] * a0 + Wso[l][0][1] * a1 + Wso[l][0][2] * a2 + Bso[l][0];
            float s1 = Wso[l][1][0] * a0 + Wso[l][1][1] * a1 + Wso[l][1][2] * a2 + Bso[l][1];
            float s2 = Wso[l][2][0] * a0 + Wso[l][2][1] * a1 + Wso[l][2][2] * a2 + Bso[l][2];
            ln3n(y0 + s0, y1 + s1, y2 + s2,
                 N1w[l][0], N1w[l][1], N1w[l][2], N1b[l][0], N1b[l][1], N1b[l][2],
                 y0, y1, y2);

            // ---- cross-attention over memory (64 keys)
            float p0 = Wcq[l][0][0] * y0 + Wcq[l][0][1] * y1 + Wcq[l][0][2] * y2 + Bcq[l][0];
            float p1 = Wcq[l][1][0] * y0 + Wcq[l][1][1] * y1 + Wcq[l][1][2] * y2 + Bcq[l][1];
            float p2 = Wcq[l][2][0] * y0 + Wcq[l][2][1] * y1 + Wcq[l][2][2] * y2 + Bcq[l][2];
            float sc2 = (p0 * ck[l][0] + p1 * ck[l][1] + p2 * ck[l][2]) * rs3;
            float e2 = __expf(sc2);
            float cs  = wave_sum_l63(e2);
            float cw0 = wave_sum_l63(e2 * cv[l][0]);
            float cw1 = wave_sum_l63(e2 * cv[l][1]);
            float cw2 = wave_sum_l63(e2 * cv[l][2]);
            inv = __builtin_amdgcn_rcpf(bcast63(cs));
            a0 = bcast63(cw0) * inv; a1 = bcast63(cw1) * inv; a2 = bcast63(cw2) * inv;
            float c0 = Wco[l][0][0] * a0 + Wco[l][0][1] * a1 + Wco[l][0][2] * a2 + Bco[l][0];
            float c1 = Wco[l][1][0] * a0 + Wco[l][1][1] * a1 + Wco[l][1][2] * a2 + Bco[l][1];
            float c2 = Wco[l][2][0] * a0 + Wco[l][2][1] * a1 + Wco[l][2][2] * a2 + Bco[l][2];
            ln3n(y0 + c0, y1 + c1, y2 + c2,
                 N2w[l][0], N2w[l][1], N2w[l][2], N2b[l][0], N2b[l][1], N2b[l][2],
                 y0, y1, y2);

            // ---- feed-forward 3 -> 4 -> 3 (relu)
            float h[4];
            #pragma unroll
            for (int f = 0; f < 4; ++f)
                h[f] = fmaxf(F1w[l][f][0] * y0 + F1w[l][f][1] * y1 + F1w[l][f][2] * y2 + F1b[l][f], 0.f);
            float f0 = F2w[l][0][0] * h[0] + F2w[l][0][1] * h[1] + F2w[l][0][2] * h[2] + F2w[l][0][3] * h[3] + F2b[l][0];
            float f1 = F2w[l][1][0] * h[0] + F2w[l][1][1] * h[1] + F2w[l][1][2] * h[2] + F2w[l][1][3] * h[3] + F2b[l][1];
            float f2 = F2w[l][2][0] * h[0] + F2w[l][2][1] * h[1] + F2w[l][2][2] * h[2] + F2w[l][2][3] * h[3] + F2b[l][2];
            ln3n(y0 + f0, y1 + f1, y2 + f2,
                 N3w[l][0], N3w[l][1], N3w[l][2], N3b[l][0], N3b[l][1], N3b[l][2],
                 y0, y1, y2);
        }
        // tgt[:, i+1] = decode(tgt)[:, i]
        if (lane == 0) {
            out[(b * S_ + i + 1) * 5 + 0] = y0;
            out[(b * S_ + i + 1) * 5 + 1] = y1;
            out[(b * S_ + i + 1) * 5 + 2] = y2;
        }
    }
}

// ---------------------------------------------------------------------------
extern "C" void kernel_launch(void* const* d_in, const int* in_sizes, int n_in,
                              void* d_out, int out_size, void* d_ws, size_t ws_size,
                              hipStream_t stream) {
    const float* src  = (const float*)d_in[0];
    const float* wemb = (const float*)d_in[1];
    const float* semb = (const float*)d_in[2];

    float* mem = (float*)d_ws;           // [B,S,3] scratch
    float* out = (float*)d_out;          // [B,S,5]

    enc_kernel<<<B_, 256, 0, stream>>>(
        src, wemb, semb,
        (const float*)d_in[3],  (const float*)d_in[4],
        (const float*)d_in[5],  (const float*)d_in[6],
        (const float*)d_in[7],  (const float*)d_in[8],
        (const float*)d_in[9],  (const float*)d_in[10],
        (const float*)d_in[11], (const float*)d_in[12],
        (const float*)d_in[13], (const float*)d_in[14],
        (const float*)d_in[15], (const float*)d_in[16],
        (const float*)d_in[17], (const float*)d_in[18],
        mem, out);

    dec_kernel<<<B_, 64, 0, stream>>>(
        mem,
        (const float*)d_in[19], (const float*)d_in[20],
        (const float*)d_in[21], (const float*)d_in[22],
        (const float*)d_in[23], (const float*)d_in[24],
        (const float*)d_in[25], (const float*)d_in[26],
        (const float*)d_in[27], (const float*)d_in[28],
        (const float*)d_in[29], (const float*)d_in[30],
        (const float*)d_in[31], (const float*)d_in[32],
        (const float*)d_in[33], (const float*)d_in[34],
        (const float*)d_in[35], (const float*)d_in[36],
        out);
}

// Round 5
// 377.809 us; speedup vs baseline: 1.7162x; 1.1040x over previous
//
#include <hip/hip_runtime.h>
#include <math.h>

#define B_ 64
#define S_ 64
#define U_ 16
#define EMB_ 10
#define D_ 34
#define DD_ 3
#define FF_ 4
#define NL_ 4

// ---------------------------------------------------------------------------
// Kernel A: embedding + pos-encoding quirk + 4 post-norm encoder layers +
// final LN + projection to memory[B,S,3] (stored in d_ws).
// One block per batch element, 512 threads (8 waves, 2/SIMD for TLP).
// Attention is parallelized 4-way over the key dimension with an LDS
// partial-softmax combine.
// ---------------------------------------------------------------------------
__global__ __launch_bounds__(512) void enc_kernel(
    const float* __restrict__ src, const float* __restrict__ wemb,
    const float* __restrict__ semb,
    const float* __restrict__ qkv_w, const float* __restrict__ qkv_b,
    const float* __restrict__ out_w, const float* __restrict__ out_b,
    const float* __restrict__ ln1_w, const float* __restrict__ ln1_b,
    const float* __restrict__ lin1_w, const float* __restrict__ lin1_b,
    const float* __restrict__ lin2_w, const float* __restrict__ lin2_b,
    const float* __restrict__ ln2_w, const float* __restrict__ ln2_b,
    const float* __restrict__ norm_w, const float* __restrict__ norm_b,
    const float* __restrict__ eo_w, const float* __restrict__ eo_b,
    float* __restrict__ mem, float* __restrict__ out)
{
    const int b = blockIdx.x;
    const int tid = threadIdx.x;

    __shared__ float xs[S_][D_ + 1];
    __shared__ float qs[S_][D_];
    __shared__ float ks[S_][D_];
    __shared__ float vs[S_][D_];
    __shared__ float att[S_][D_];
    __shared__ float ffh[S_][FF_];
    __shared__ float tmp[S_][D_ + 1];
    __shared__ float pacc[4][128][19];      // partial softmax: 17 acc + ssum; stride 19 = conflict-free
    // per-layer weight staging
    __shared__ float wq_s[3 * D_ * D_];
    __shared__ float wo_s[D_ * D_];
    __shared__ float w1_s[FF_ * D_];
    __shared__ float w2_s[D_ * FF_];
    __shared__ float bq_s[3 * D_], bo_s[D_], b1_s[FF_], b2_s[D_];
    __shared__ float l1w_s[D_], l1b_s[D_], l2w_s[D_], l2b_s[D_];

    // ---- embed_lyrics + positional encoding (pe row b added to ALL positions)
    const float negln = -logf(10000.0f) / (float)D_;
    #pragma unroll
    for (int rep = 0; rep < 5; ++rep) {
        int idx = tid + rep * 512;
        if (idx < S_ * D_) {
            int pos = idx / D_, d = idx % D_;
            float v;
            if (d < U_ - 2) {
                v = src[(b * S_ + pos) * U_ + d];
            } else if (d < U_ - 2 + EMB_) {
                int wi = (int)src[(b * S_ + pos) * U_ + (U_ - 2)];
                v = wemb[wi * EMB_ + (d - (U_ - 2))];
            } else {
                int si = (int)src[(b * S_ + pos) * U_ + (U_ - 1)];
                v = semb[si * EMB_ + (d - (U_ - 2 + EMB_))];
            }
            int k = d >> 1;
            float div = expf((float)(2 * k) * negln);
            float ang = (float)b * div;
            v += (d & 1) ? cosf(ang) : sinf(ang);
            xs[pos][d] = v;
        }
    }
    __syncthreads();

    const float rs17 = 0.24253562503633297f;  // 1/sqrt(17)

    for (int l = 0; l < NL_; ++l) {
        // ---- stage this layer's weights into LDS (coalesced)
        for (int t = tid; t < 3 * D_ * D_; t += 512) wq_s[t] = qkv_w[l * 3 * D_ * D_ + t];
        for (int t = tid; t < D_ * D_; t += 512)     wo_s[t] = out_w[l * D_ * D_ + t];
        for (int t = tid; t < FF_ * D_; t += 512)    w1_s[t] = lin1_w[l * FF_ * D_ + t];
        for (int t = tid; t < D_ * FF_; t += 512)    w2_s[t] = lin2_w[l * D_ * FF_ + t];
        for (int t = tid; t < 3 * D_ + 6 * D_ + FF_; t += 512) {
            if      (t < 3 * D_)          bq_s[t]            = qkv_b[l * 3 * D_ + t];
            else if (t < 3 * D_ + D_)     bo_s[t - 3 * D_]   = out_b[l * D_ + (t - 3 * D_)];
            else if (t < 3 * D_ + 2 * D_) l1w_s[t - 4 * D_]  = ln1_w[l * D_ + (t - 4 * D_)];
            else if (t < 3 * D_ + 3 * D_) l1b_s[t - 5 * D_]  = ln1_b[l * D_ + (t - 5 * D_)];
            else if (t < 3 * D_ + 4 * D_) l2w_s[t - 6 * D_]  = ln2_w[l * D_ + (t - 6 * D_)];
            else if (t < 3 * D_ + 5 * D_) l2b_s[t - 7 * D_]  = ln2_b[l * D_ + (t - 7 * D_)];
            else if (t < 3 * D_ + 6 * D_) b2_s[t - 8 * D_]   = lin2_b[l * D_ + (t - 8 * D_)];
            else                          b1_s[t - 9 * D_]   = lin1_b[l * FF_ + (t - 9 * D_)];
        }
        __syncthreads();

        // ---- qkv projection: 6528 outputs, 13 reps of 512
        #pragma unroll 2
        for (int rep = 0; rep < 13; ++rep) {
            int idx = tid + rep * 512;
            if (idx < S_ * 3 * D_) {
                int pos = idx / (3 * D_), r = idx % (3 * D_);
                const float* wrow = wq_s + r * D_;
                float aE = bq_s[r], aO = 0.f;
                #pragma unroll
                for (int d = 0; d < D_; d += 2) {
                    aE += xs[pos][d] * wrow[d];
                    aO += xs[pos][d + 1] * wrow[d + 1];
                }
                float acc = aE + aO;
                if (r < D_)          qs[pos][r] = acc;
                else if (r < 2 * D_) ks[pos][r - D_] = acc;
                else                 vs[pos][r - 2 * D_] = acc;
            }
        }
        __syncthreads();

        // ---- attention, 4-way key-parallel: tid = c*128 + h*64 + qi
        {
            int c = tid >> 7, hq = tid & 127;
            int h = hq >> 6, qi = hq & 63;
            int off = h * 17;
            float qv[17], acc[17];
            #pragma unroll
            for (int d = 0; d < 17; ++d) { qv[d] = qs[qi][off + d]; acc[d] = 0.f; }
            float ssum = 0.f;
            int j0 = c * 16;
            #pragma unroll 2
            for (int jj = 0; jj < 16; ++jj) {
                int j = j0 + jj;
                float sE = 0.f, sO = 0.f;
                #pragma unroll
                for (int d = 0; d < 16; d += 2) {
                    sE += qv[d] * ks[j][off + d];
                    sO += qv[d + 1] * ks[j][off + d + 1];
                }
                float sc = sE + sO + qv[16] * ks[j][off + 16];
                float e = __expf(sc * rs17);
                ssum += e;
                #pragma unroll
                for (int d = 0; d < 17; ++d) acc[d] += e * vs[j][off + d];
            }
            #pragma unroll
            for (int d = 0; d < 17; ++d) pacc[c][hq][d] = acc[d];
            pacc[c][hq][17] = ssum;
        }
        __syncthreads();

        // ---- combine partial softmax (128 threads)
        if (tid < 128) {
            int h = tid >> 6, qi = tid & 63;
            int off = h * 17;
            float ssum = pacc[0][tid][17] + pacc[1][tid][17] +
                         pacc[2][tid][17] + pacc[3][tid][17];
            float inv = 1.f / ssum;
            #pragma unroll
            for (int d = 0; d < 17; ++d)
                att[qi][off + d] = (pacc[0][tid][d] + pacc[1][tid][d] +
                                    pacc[2][tid][d] + pacc[3][tid][d]) * inv;
        }
        __syncthreads();

        // ---- out proj + residual: 2176 outputs, 5 reps
        #pragma unroll 2
        for (int rep = 0; rep < 5; ++rep) {
            int idx = tid + rep * 512;
            if (idx < S_ * D_) {
                int pos = idx / D_, d = idx % D_;
                const float* wrow = wo_s + d * D_;
                float aE = bo_s[d], aO = 0.f;
                #pragma unroll
                for (int e = 0; e < D_; e += 2) {
                    aE += att[pos][e] * wrow[e];
                    aO += att[pos][e + 1] * wrow[e + 1];
                }
                tmp[pos][d] = xs[pos][d] + aE + aO;
            }
        }
        __syncthreads();

        // ---- LN1
        if (tid < S_) {
            int row = tid;
            float sA = 0.f, sB = 0.f;
            #pragma unroll
            for (int d = 0; d < D_; d += 2) { sA += tmp[row][d]; sB += tmp[row][d + 1]; }
            float mu = (sA + sB) * (1.0f / D_);
            float vA = 0.f, vB = 0.f;
            #pragma unroll
            for (int d = 0; d < D_; d += 2) {
                float t0 = tmp[row][d] - mu;     vA += t0 * t0;
                float t1 = tmp[row][d + 1] - mu; vB += t1 * t1;
            }
            float rstd = rsqrtf((vA + vB) * (1.0f / D_) + 1e-5f);
            #pragma unroll
            for (int d = 0; d < D_; ++d)
                xs[row][d] = (tmp[row][d] - mu) * rstd * l1w_s[d] + l1b_s[d];
        }
        __syncthreads();

        // ---- FF1 (34 -> 4, relu): 256 outputs
        if (tid < 256) {
            int pos = tid >> 2, f = tid & 3;
            const float* wrow = w1_s + f * D_;
            float aE = b1_s[f], aO = 0.f;
            #pragma unroll
            for (int d = 0; d < D_; d += 2) {
                aE += xs[pos][d] * wrow[d];
                aO += xs[pos][d + 1] * wrow[d + 1];
            }
            ffh[pos][f] = fmaxf(aE + aO, 0.f);
        }
        __syncthreads();

        // ---- FF2 (4 -> 34) + residual: 2176 outputs, 5 reps
        #pragma unroll 2
        for (int rep = 0; rep < 5; ++rep) {
            int idx = tid + rep * 512;
            if (idx < S_ * D_) {
                int pos = idx / D_, d = idx % D_;
                const float* wrow = w2_s + d * FF_;
                float acc = b2_s[d] + ffh[pos][0] * wrow[0] + ffh[pos][1] * wrow[1] +
                            ffh[pos][2] * wrow[2] + ffh[pos][3] * wrow[3];
                tmp[pos][d] = xs[pos][d] + acc;
            }
        }
        __syncthreads();

        // ---- LN2
        if (tid < S_) {
            int row = tid;
            float sA = 0.f, sB = 0.f;
            #pragma unroll
            for (int d = 0; d < D_; d += 2) { sA += tmp[row][d]; sB += tmp[row][d + 1]; }
            float mu = (sA + sB) * (1.0f / D_);
            float vA = 0.f, vB = 0.f;
            #pragma unroll
            for (int d = 0; d < D_; d += 2) {
                float t0 = tmp[row][d] - mu;     vA += t0 * t0;
                float t1 = tmp[row][d + 1] - mu; vB += t1 * t1;
            }
            float rstd = rsqrtf((vA + vB) * (1.0f / D_) + 1e-5f);
            #pragma unroll
            for (int d = 0; d < D_; ++d)
                xs[row][d] = (tmp[row][d] - mu) * rstd * l2w_s[d] + l2b_s[d];
        }
        __syncthreads();
    }

    // ---- final LayerNorm (norm_w/norm_b)
    if (tid < S_) {
        int row = tid;
        float sA = 0.f, sB = 0.f;
        #pragma unroll
        for (int d = 0; d < D_; d += 2) { sA += xs[row][d]; sB += xs[row][d + 1]; }
        float mu = (sA + sB) * (1.0f / D_);
        float vA = 0.f, vB = 0.f;
        #pragma unroll
        for (int d = 0; d < D_; d += 2) {
            float t0 = xs[row][d] - mu;     vA += t0 * t0;
            float t1 = xs[row][d + 1] - mu; vB += t1 * t1;
        }
        float rstd = rsqrtf((vA + vB) * (1.0f / D_) + 1e-5f);
        #pragma unroll
        for (int d = 0; d < D_; ++d)
            xs[row][d] = (xs[row][d] - mu) * rstd * norm_w[d] + norm_b[d];
    }
    __syncthreads();

    // ---- memory = x @ eo_w.T + eo_b  -> d_ws (192 outputs)
    if (tid < S_ * DD_) {
        int pos = tid / DD_, r = tid % DD_;
        const float* wrow = eo_w + r * D_;
        float aE = eo_b[r], aO = 0.f;
        #pragma unroll
        for (int d = 0; d < D_; d += 2) {
            aE += xs[pos][d] * wrow[d];
            aO += xs[pos][d + 1] * wrow[d + 1];
        }
        mem[(b * S_ + pos) * DD_ + r] = aE + aO;
    }

    // ---- pass-through output columns 3,4 (word / syllable idx)
    if (tid < S_) {
        out[(b * S_ + tid) * 5 + 3] = src[(b * S_ + tid) * U_ + (U_ - 2)];
        out[(b * S_ + tid) * 5 + 4] = src[(b * S_ + tid) * U_ + (U_ - 1)];
    }
}

// ---------------------------------------------------------------------------
// Kernel B: incremental autoregressive decoder. One block = one wave = one
// batch element. Lane j owns position j's self/cross K/V. DPP softmax sums.
// Attention/LN1/LN2 weights pinned in VGPRs (336 values); FF-tail weights
// (F1/F2/LN3, 37/layer) staged in LDS once and read as float4 + PIN at the
// TOP of each layer body -> ~800cy of SA/CA slack hides the ds_read latency
// and removes R4's per-layer s_load lgkmcnt drains. 1/sqrt(3) is folded into
// the q-projection weights.
// ---------------------------------------------------------------------------
#define PIN(x) asm volatile("" : "+v"(x))

template <int CTRL>
__device__ __forceinline__ float dpp_add(float v) {
    int t = __builtin_amdgcn_update_dpp(0, __float_as_int(v), CTRL, 0xf, 0xf, true);
    return v + __int_as_float(t);
}

// full-wave sum; valid in lane 63 only
__device__ __forceinline__ float wave_sum_l63(float v) {
    v = dpp_add<0x111>(v);  // row_shr:1
    v = dpp_add<0x112>(v);  // row_shr:2
    v = dpp_add<0x114>(v);  // row_shr:4
    v = dpp_add<0x118>(v);  // row_shr:8
    v = dpp_add<0x142>(v);  // row_bcast:15
    v = dpp_add<0x143>(v);  // row_bcast:31
    return v;
}

__device__ __forceinline__ float bcast63(float v) {
    return __int_as_float(__builtin_amdgcn_readlane(__float_as_int(v), 63));
}

__device__ __forceinline__ void ln3n(float z0, float z1, float z2,
                                     float w0, float w1, float w2,
                                     float b0, float b1, float b2,
                                     float& o0, float& o1, float& o2) {
    float mu = (z0 + z1 + z2) * (1.0f / 3.0f);
    float d0 = z0 - mu, d1 = z1 - mu, d2 = z2 - mu;
    float var = (d0 * d0 + d1 * d1 + d2 * d2) * (1.0f / 3.0f);
    float rstd = __builtin_amdgcn_rsqf(var + 1e-5f);
    o0 = d0 * rstd * w0 + b0;
    o1 = d1 * rstd * w1 + b1;
    o2 = d2 * rstd * w2 + b2;
}

__global__ __launch_bounds__(64, 1) void dec_kernel(
    const float* __restrict__ mem,
    const float* __restrict__ sa_qkv_w, const float* __restrict__ sa_qkv_b,
    const float* __restrict__ sa_out_w, const float* __restrict__ sa_out_b,
    const float* __restrict__ gln1_w, const float* __restrict__ gln1_b,
    const float* __restrict__ ca_qkv_w, const float* __restrict__ ca_qkv_b,
    const float* __restrict__ ca_out_w, const float* __restrict__ ca_out_b,
    const float* __restrict__ gln2_w, const float* __restrict__ gln2_b,
    const float* __restrict__ l1_w, const float* __restrict__ l1_b,
    const float* __restrict__ l2_w, const float* __restrict__ l2_b,
    const float* __restrict__ gln3_w, const float* __restrict__ gln3_b,
    float* __restrict__ out)
{
    const int b = blockIdx.x;
    const int lane = threadIdx.x;
    const float rs3 = 0.5773502691896258f;  // 1/sqrt(3)

    // ---- FF-tail weight stage (F1w 0..11, F1b 12..15, F2w 16..27,
    //      F2b 28..30, N3w 31..33, N3b 34..36) — 40-slot rows, 16B aligned
    __shared__ __align__(16) float fst[NL_][40];
    for (int t = lane; t < NL_ * 40; t += 64) {
        int l = t / 40, s = t % 40;
        float v = 0.f;
        if      (s < 12) v = l1_w[l * 12 + s];
        else if (s < 16) v = l1_b[l * 4 + (s - 12)];
        else if (s < 28) v = l2_w[l * 12 + (s - 16)];
        else if (s < 31) v = l2_b[l * 3 + (s - 28)];
        else if (s < 34) v = gln3_w[l * 3 + (s - 31)];
        else if (s < 37) v = gln3_b[l * 3 + (s - 34)];
        fst[l][s] = v;
    }
    __syncthreads();

    // ---- persistent pinned weights (336 values)
    float Wsq[NL_][9][3], Bsq[NL_][9];
    float Wso[NL_][3][3], Bso[NL_][3];
    float N1w[NL_][3], N1b[NL_][3];
    float Wcq[NL_][3][3], Bcq[NL_][3];
    float Wco[NL_][3][3], Bco[NL_][3];
    float N2w[NL_][3], N2b[NL_][3];

    #pragma unroll
    for (int l = 0; l < NL_; ++l) {
        #pragma unroll
        for (int r = 0; r < 9; ++r) {
            float sc = (r < 3) ? rs3 : 1.0f;   // fold 1/sqrt(3) into q rows
            Bsq[l][r] = sa_qkv_b[l * 9 + r] * sc;
            #pragma unroll
            for (int c = 0; c < 3; ++c) Wsq[l][r][c] = sa_qkv_w[l * 27 + r * 3 + c] * sc;
        }
        #pragma unroll
        for (int r = 0; r < 3; ++r) {
            Bso[l][r] = sa_out_b[l * 3 + r];
            Bcq[l][r] = ca_qkv_b[l * 9 + r] * rs3;
            Bco[l][r] = ca_out_b[l * 3 + r];
            N1w[l][r] = gln1_w[l * 3 + r];  N1b[l][r] = gln1_b[l * 3 + r];
            N2w[l][r] = gln2_w[l * 3 + r];  N2b[l][r] = gln2_b[l * 3 + r];
            #pragma unroll
            for (int c = 0; c < 3; ++c) {
                Wso[l][r][c] = sa_out_w[l * 9 + r * 3 + c];
                Wcq[l][r][c] = ca_qkv_w[l * 27 + r * 3 + c] * rs3;
                Wco[l][r][c] = ca_out_w[l * 9 + r * 3 + c];
            }
        }
    }

    // ---- cross-attn K/V per lane (memory position = lane)
    float m0 = mem[(b * S_ + lane) * DD_ + 0];
    float m1 = mem[(b * S_ + lane) * DD_ + 1];
    float m2 = mem[(b * S_ + lane) * DD_ + 2];

    float ck[NL_][3], cv[NL_][3];
    #pragma unroll
    for (int l = 0; l < NL_; ++l) {
        #pragma unroll
        for (int r = 0; r < 3; ++r) {
            ck[l][r] = ca_qkv_w[l * 27 + (3 + r) * 3 + 0] * m0 +
                       ca_qkv_w[l * 27 + (3 + r) * 3 + 1] * m1 +
                       ca_qkv_w[l * 27 + (3 + r) * 3 + 2] * m2 + ca_qkv_b[l * 9 + 3 + r];
            cv[l][r] = ca_qkv_w[l * 27 + (6 + r) * 3 + 0] * m0 +
                       ca_qkv_w[l * 27 + (6 + r) * 3 + 1] * m1 +
                       ca_qkv_w[l * 27 + (6 + r) * 3 + 2] * m2 + ca_qkv_b[l * 9 + 6 + r];
        }
    }

    // ---- pin the chain-critical set into VGPRs
    #pragma unroll
    for (int l = 0; l < NL_; ++l) {
        #pragma unroll
        for (int r = 0; r < 9; ++r) {
            PIN(Bsq[l][r]);
            #pragma unroll
            for (int c = 0; c < 3; ++c) PIN(Wsq[l][r][c]);
        }
        #pragma unroll
        for (int r = 0; r < 3; ++r) {
            PIN(Bso[l][r]); PIN(Bcq[l][r]); PIN(Bco[l][r]);
            PIN(N1w[l][r]); PIN(N1b[l][r]); PIN(N2w[l][r]); PIN(N2b[l][r]);
            #pragma unroll
            for (int c = 0; c < 3; ++c) { PIN(Wso[l][r][c]); PIN(Wcq[l][r][c]); PIN(Wco[l][r][c]); }
        }
    }

    // self-attn KV cache: lane j owns position j
    float sk[NL_][3] = {{0.f}}, sv[NL_][3] = {{0.f}};

    // tgt[:,0,:] = 0 (never overwritten by the scan)
    if (lane < 3) out[(b * S_ + 0) * 5 + lane] = 0.f;

    float y0 = 0.f, y1 = 0.f, y2 = 0.f;

    for (int i = 0; i < S_ - 1; ++i) {
        #pragma unroll
        for (int l = 0; l < NL_; ++l) {
            // ---- FF-tail weights: issue LDS reads NOW (used after SA+CA,
            // ~800cy of slack); PIN keeps them in VGPRs at this point
            float wv[40];
            {
                const float4* fp = (const float4*)fst[l];
                #pragma unroll
                for (int k = 0; k < 10; ++k) {
                    float4 t4 = fp[k];
                    wv[4 * k + 0] = t4.x; wv[4 * k + 1] = t4.y;
                    wv[4 * k + 2] = t4.z; wv[4 * k + 3] = t4.w;
                }
                #pragma unroll
                for (int k = 0; k < 37; ++k) PIN(wv[k]);
            }

            // ---- causal self-attention (incremental; q pre-scaled by rs3)
            float q[3], kn[3], vn[3];
            #pragma unroll
            for (int r = 0; r < 3; ++r) {
                q[r]  = Wsq[l][r][0] * y0 + Wsq[l][r][1] * y1 + Wsq[l][r][2] * y2 + Bsq[l][r];
                kn[r] = Wsq[l][3 + r][0] * y0 + Wsq[l][3 + r][1] * y1 + Wsq[l][3 + r][2] * y2 + Bsq[l][3 + r];
                vn[r] = Wsq[l][6 + r][0] * y0 + Wsq[l][6 + r][1] * y1 + Wsq[l][6 + r][2] * y2 + Bsq[l][6 + r];
            }
            if (lane == i) {
                #pragma unroll
                for (int r = 0; r < 3; ++r) { sk[l][r] = kn[r]; sv[l][r] = vn[r]; }
            }
            float sc = q[0] * sk[l][0] + q[1] * sk[l][1] + q[2] * sk[l][2];
            float e = (lane <= i) ? __expf(sc) : 0.f;
            float es  = wave_sum_l63(e);
            float ev0 = wave_sum_l63(e * sv[l][0]);
            float ev1 = wave_sum_l63(e * sv[l][1]);
            float ev2 = wave_sum_l63(e * sv[l][2]);
            float inv = __builtin_amdgcn_rcpf(bcast63(es));
            float a0 = bcast63(ev0) * inv, a1 = bcast63(ev1) * inv, a2 = bcast63(ev2) * inv;
            float s0 = Wso[l][0][0] * a0 + Wso[l][0][1] * a1 + Wso[l][0][2] * a2 + Bso[l][0];
            float s1 = Wso[l][1][0] * a0 + Wso[l][1][1] * a1 + Wso[l][1][2] * a2 + Bso[l][1];
            float s2 = Wso[l][2][0] * a0 + Wso[l][2][1] * a1 + Wso[l][2][2] * a2 + Bso[l][2];
            ln3n(y0 + s0, y1 + s1, y2 + s2,
                 N1w[l][0], N1w[l][1], N1w[l][2], N1b[l][0], N1b[l][1], N1b[l][2],
                 y0, y1, y2);

            // ---- cross-attention over memory (64 keys; p pre-scaled by rs3)
            float p0 = Wcq[l][0][0] * y0 + Wcq[l][0][1] * y1 + Wcq[l][0][2] * y2 + Bcq[l][0];
            float p1 = Wcq[l][1][0] * y0 + Wcq[l][1][1] * y1 + Wcq[l][1][2] * y2 + Bcq[l][1];
            float p2 = Wcq[l][2][0] * y0 + Wcq[l][2][1] * y1 + Wcq[l][2][2] * y2 + Bcq[l][2];
            float sc2 = p0 * ck[l][0] + p1 * ck[l][1] + p2 * ck[l][2];
            float e2 = __expf(sc2);
            float cs  = wave_sum_l63(e2);
            float cw0 = wave_sum_l63(e2 * cv[l][0]);
            float cw1 = wave_sum_l63(e2 * cv[l][1]);
            float cw2 = wave_sum_l63(e2 * cv[l][2]);
            inv = __builtin_amdgcn_rcpf(bcast63(cs));
            a0 = bcast63(cw0) * inv; a1 = bcast63(cw1) * inv; a2 = bcast63(cw2) * inv;
            float c0 = Wco[l][0][0] * a0 + Wco[l][0][1] * a1 + Wco[l][0][2] * a2 + Bco[l][0];
            float c1 = Wco[l][1][0] * a0 + Wco[l][1][1] * a1 + Wco[l][1][2] * a2 + Bco[l][1];
            float c2 = Wco[l][2][0] * a0 + Wco[l][2][1] * a1 + Wco[l][2][2] * a2 + Bco[l][2];
            ln3n(y0 + c0, y1 + c1, y2 + c2,
                 N2w[l][0], N2w[l][1], N2w[l][2], N2b[l][0], N2b[l][1], N2b[l][2],
                 y0, y1, y2);

            // ---- feed-forward 3 -> 4 -> 3 (relu) from LDS-staged wv[]
            float h[4];
            #pragma unroll
            for (int f = 0; f < 4; ++f)
                h[f] = fmaxf(wv[f * 3 + 0] * y0 + wv[f * 3 + 1] * y1 + wv[f * 3 + 2] * y2 + wv[12 + f], 0.f);
            float f0 = wv[16] * h[0] + wv[17] * h[1] + wv[18] * h[2] + wv[19] * h[3] + wv[28];
            float f1 = wv[20] * h[0] + wv[21] * h[1] + wv[22] * h[2] + wv[23] * h[3] + wv[29];
            float f2 = wv[24] * h[0] + wv[25] * h[1] + wv[26] * h[2] + wv[27] * h[3] + wv[30];
            ln3n(y0 + f0, y1 + f1, y2 + f2,
                 wv[31], wv[32], wv[33], wv[34], wv[35], wv[36],
                 y0, y1, y2);
        }
        // tgt[:, i+1] = decode(tgt)[:, i]
        if (lane == 0) {
            out[(b * S_ + i + 1) * 5 + 0] = y0;
            out[(b * S_ + i + 1) * 5 + 1] = y1;
            out[(b * S_ + i + 1) * 5 + 2] = y2;
        }
    }
}

// ---------------------------------------------------------------------------
extern "C" void kernel_launch(void* const* d_in, const int* in_sizes, int n_in,
                              void* d_out, int out_size, void* d_ws, size_t ws_size,
                              hipStream_t stream) {
    const float* src  = (const float*)d_in[0];
    const float* wemb = (const float*)d_in[1];
    const float* semb = (const float*)d_in[2];

    float* mem = (float*)d_ws;           // [B,S,3] scratch
    float* out = (float*)d_out;          // [B,S,5]

    enc_kernel<<<B_, 512, 0, stream>>>(
        src, wemb, semb,
        (const float*)d_in[3],  (const float*)d_in[4],
        (const float*)d_in[5],  (const float*)d_in[6],
        (const float*)d_in[7],  (const float*)d_in[8],
        (const float*)d_in[9],  (const float*)d_in[10],
        (const float*)d_in[11], (const float*)d_in[12],
        (const float*)d_in[13], (const float*)d_in[14],
        (const float*)d_in[15], (const float*)d_in[16],
        (const float*)d_in[17], (const float*)d_in[18],
        mem, out);

    dec_kernel<<<B_, 64, 0, stream>>>(
        mem,
        (const float*)d_in[19], (const float*)d_in[20],
        (const float*)d_in[21], (const float*)d_in[22],
        (const float*)d_in[23], (const float*)d_in[24],
        (const float*)d_in[25], (const float*)d_in[26],
        (const float*)d_in[27], (const float*)d_in[28],
        (const float*)d_in[29], (const float*)d_in[30],
        (const float*)d_in[31], (const float*)d_in[32],
        (const float*)d_in[33], (const float*)d_in[34],
        (const float*)d_in[35], (const float*)d_in[36],
        out);
}